// Round 5
// baseline (403.020 us; speedup 1.0000x reference)
//
#include <hip/hip_runtime.h>

// CRF loss, S=512, B=256, L=128; out = sum_b log_z_b - gold.
//
// Scan: one wave per 16 batches (16 blocks x 64 threads), ALL state in
// registers. Step t: D[j][b] = sum_k~ A[j][k~] * W~[k~][b] via 32x
// __builtin_amdgcn_mfma_f32_16x16x32_bf16 (8 j-tiles x 4 k-chunks), then
// w_new = D * xs, packed back to bf16 B-fragments IN-LANE (no LDS, no
// barriers, no cross-lane moves): the k-permutation pi baked into A makes
// the MFMA C/D register layout coincide with the B-fragment layout.
//   pi: j = 16jt + 4g + r  ->  k~ = 32*(jt>>1) + 8g + 4*(jt&1) + r
//   A[j][k~] = exp(T[pi^-1(k~)][j]),
//   pi^-1(32ch + 8g + e) = 32ch + 16*(e>>2) + 4g + (e&3).
// Fragment conventions (A/B: m|n=lane&15, k=8*(lane>>4)+elem; C/D:
// n=lane&15, m=4*(lane>>4)+reg) are the ones R2's PASSING kernel used.
//
// R3/R4 NaN'd with inline-asm MFMA despite hand fences => garbage-register
// class bug in the asm surface (all math is positive & bounded, so NaN is
// impossible in correct dataflow). R5: builtins only, zero inline asm —
// compiler owns hazards/waits/scheduling.
//
// Renorm every 4 steps by per-batch MAX exponent (exact power-of-2 scale,
// int ls2 accumulator): after renorm values in [1,2), growth <= ~2^16/step
// => fp32 overflow structurally impossible.
//
// xs = exp(emit) precomputed as packed bf16 by a memory-bound full-GPU
// kernel into d_ws (33.5 MB); fallback computes exp2 in-scan if ws is small.

#define LOG2E 1.4426950408889634f
#define LN2F  0.6931471805599453f

typedef float        f32x4  __attribute__((ext_vector_type(4)));
typedef unsigned int u32x4  __attribute__((ext_vector_type(4)));
typedef short        bf16x8 __attribute__((ext_vector_type(8)));

__device__ __forceinline__ unsigned f2bf(float a) {
    unsigned u = __float_as_uint(a);
    return (u + 0x7FFFu + ((u >> 16) & 1u)) >> 16;   // RNE
}
__device__ __forceinline__ unsigned pack2bf(float a, float b) {
    return f2bf(a) | (f2bf(b) << 16);
}
__device__ __forceinline__ float bflo(unsigned w) { return __uint_as_float(w << 16); }
__device__ __forceinline__ float bfhi(unsigned w) { return __uint_as_float(w & 0xFFFF0000u); }

#define MFMA(acc, Aop, Bop) \
    acc = __builtin_amdgcn_mfma_f32_16x16x32_bf16( \
        __builtin_bit_cast(bf16x8, Aop), __builtin_bit_cast(bf16x8, Bop), acc, 0, 0, 0)

// One scan step. SLOT: prefetch slot (literal). TPF: t to prefetch.
// DOPF/RN/LAST: literal flags. Uses kernel scope: Afr, Bf, xbu, xbf, xsu,
// emf4, lb, ls2, fin.
#define STEP(SLOT, TPF, DOPF, RN, LAST) do {                                  \
    f32x4 ac[8];                                                              \
    _Pragma("unroll") for (int jt = 0; jt < 8; ++jt) {                        \
        ac[jt] = (f32x4){0.f, 0.f, 0.f, 0.f};                                 \
        _Pragma("unroll") for (int ch = 0; ch < 4; ++ch)                      \
            MFMA(ac[jt], Afr[ch][jt], Bf[ch]);                                \
    }                                                                         \
    float xv[8][4];                                                           \
    if constexpr (XSP) {                                                      \
        _Pragma("unroll") for (int jt = 0; jt < 8; ++jt) {                    \
            uint2 xw = xbu[SLOT][jt];                                         \
            xv[jt][0] = bflo(xw.x); xv[jt][1] = bfhi(xw.x);                   \
            xv[jt][2] = bflo(xw.y); xv[jt][3] = bfhi(xw.y);                   \
        }                                                                     \
    } else {                                                                  \
        _Pragma("unroll") for (int jt = 0; jt < 8; ++jt) {                    \
            float4 xw = xbf[SLOT][jt];                                        \
            xv[jt][0] = __builtin_amdgcn_exp2f(xw.x * LOG2E);                 \
            xv[jt][1] = __builtin_amdgcn_exp2f(xw.y * LOG2E);                 \
            xv[jt][2] = __builtin_amdgcn_exp2f(xw.z * LOG2E);                 \
            xv[jt][3] = __builtin_amdgcn_exp2f(xw.w * LOG2E);                 \
        }                                                                     \
    }                                                                         \
    if (DOPF) {                                                               \
        int tp = (TPF); if (tp > 511) tp = 511;                               \
        if constexpr (XSP) {                                                  \
            _Pragma("unroll") for (int jt = 0; jt < 8; ++jt)                  \
                xbu[SLOT][jt] = xsu[8192 * tp + lb + 4 * jt];                 \
        } else {                                                              \
            _Pragma("unroll") for (int jt = 0; jt < 8; ++jt)                  \
                xbf[SLOT][jt] = emf4[8192 * tp + lb + 4 * jt];                \
        }                                                                     \
    }                                                                         \
    float vv[8][4];                                                           \
    _Pragma("unroll") for (int jt = 0; jt < 8; ++jt)                          \
        _Pragma("unroll") for (int r = 0; r < 4; ++r)                         \
            vv[jt][r] = ac[jt][r] * xv[jt][r];                                \
    if (RN) {                                                                 \
        float mx = vv[0][0];                                                  \
        _Pragma("unroll") for (int jt = 0; jt < 8; ++jt)                      \
            _Pragma("unroll") for (int r = 0; r < 4; ++r)                     \
                mx = fmaxf(mx, vv[jt][r]);                                    \
        mx = fmaxf(mx, __shfl_xor(mx, 16));                                   \
        mx = fmaxf(mx, __shfl_xor(mx, 32));                                   \
        int Ee = (__float_as_int(mx) >> 23) & 0xFF;                           \
        if (Ee > 254) Ee = 254;                                               \
        ls2 += Ee - 127;                                                      \
        float scl = __int_as_float((254 - Ee) << 23);                         \
        _Pragma("unroll") for (int jt = 0; jt < 8; ++jt)                      \
            _Pragma("unroll") for (int r = 0; r < 4; ++r)                     \
                vv[jt][r] *= scl;                                             \
    }                                                                         \
    if (LAST) {                                                               \
        fin = 0.f;                                                            \
        _Pragma("unroll") for (int jt = 0; jt < 8; ++jt)                      \
            fin += (vv[jt][0] + vv[jt][1]) + (vv[jt][2] + vv[jt][3]);         \
    } else {                                                                  \
        _Pragma("unroll") for (int ch = 0; ch < 4; ++ch) {                    \
            Bf[ch][0] = pack2bf(vv[2*ch][0],     vv[2*ch][1]);                \
            Bf[ch][1] = pack2bf(vv[2*ch][2],     vv[2*ch][3]);                \
            Bf[ch][2] = pack2bf(vv[2*ch + 1][0], vv[2*ch + 1][1]);            \
            Bf[ch][3] = pack2bf(vv[2*ch + 1][2], vv[2*ch + 1][3]);            \
        }                                                                     \
    }                                                                         \
} while (0)

// xs[t][b][j] = exp(emit[t][b][j]) as packed bf16 (memory-bound, full GPU).
__global__ __launch_bounds__(256) void crf_xs_kernel(
    const float* __restrict__ emit, unsigned* __restrict__ xs)
{
    const size_t i = (size_t)blockIdx.x * 256 + threadIdx.x;  // uint2 index
    const float4 e = ((const float4*)emit)[i];
    uint2 o;
    o.x = pack2bf(__builtin_amdgcn_exp2f(e.x * LOG2E),
                  __builtin_amdgcn_exp2f(e.y * LOG2E));
    o.y = pack2bf(__builtin_amdgcn_exp2f(e.z * LOG2E),
                  __builtin_amdgcn_exp2f(e.w * LOG2E));
    ((uint2*)xs)[i] = o;
}

template<bool XSP>
__global__ __launch_bounds__(64, 1) void crf_scan_kernel(
    const float* __restrict__ emit,
    const unsigned* __restrict__ xs,
    const float* __restrict__ Tm,
    float* __restrict__ scan_part)   // (256)
{
    const int gb = blockIdx.x;       // batch group 0..15
    const int l  = threadIdx.x;      // 0..63
    const int b  = l & 15;           // batch within group (MFMA m/n index)
    const int g  = l >> 4;           // 16-lane group
    const int bg = gb * 16 + b;
    const int lb = 32 * bg + g;      // per-lane uint2/float4 base index

    const uint2*  xsu  = (const uint2*)xs;
    const float4* emf4 = (const float4*)emit;

    // ---- constant A fragments: lane holds A[m = l&15][k = 8g + e] ----
    // A[j][k~] = exp(T[pi^-1(k~)][j]), j = 16jt + (l&15),
    // pi^-1(32ch + 8g + e) = 32ch + 16*(e>>2) + 4g + (e&3).
    u32x4 Afr[4][8];
#pragma unroll
    for (int ch = 0; ch < 4; ++ch)
#pragma unroll
        for (int p = 0; p < 4; ++p) {
            const int e0 = 2 * p, e1 = 2 * p + 1;
            const int jp0 = 32 * ch + 16 * (e0 >> 2) + 4 * g + (e0 & 3);
            const int jp1 = 32 * ch + 16 * (e1 >> 2) + 4 * g + (e1 & 3);
#pragma unroll
            for (int jt = 0; jt < 8; ++jt) {
                float a0 = __builtin_amdgcn_exp2f(Tm[jp0 * 128 + 16 * jt + b] * LOG2E);
                float a1 = __builtin_amdgcn_exp2f(Tm[jp1 * 128 + 16 * jt + b] * LOG2E);
                Afr[ch][jt][p] = pack2bf(a0, a1);
            }
        }

    // ---- t=0 init: B-frags = xs[0] (w0 = exp(emit[0])), pi-packed ----
    u32x4 Bf[4];
    if constexpr (XSP) {
        uint2 tw[8];
#pragma unroll
        for (int jt = 0; jt < 8; ++jt) tw[jt] = xsu[lb + 4 * jt];
#pragma unroll
        for (int ch = 0; ch < 4; ++ch) {
            Bf[ch][0] = tw[2 * ch].x;     Bf[ch][1] = tw[2 * ch].y;
            Bf[ch][2] = tw[2 * ch + 1].x; Bf[ch][3] = tw[2 * ch + 1].y;
        }
    } else {
        float x0[8][4];
#pragma unroll
        for (int jt = 0; jt < 8; ++jt) {
            float4 e = emf4[lb + 4 * jt];
            x0[jt][0] = __builtin_amdgcn_exp2f(e.x * LOG2E);
            x0[jt][1] = __builtin_amdgcn_exp2f(e.y * LOG2E);
            x0[jt][2] = __builtin_amdgcn_exp2f(e.z * LOG2E);
            x0[jt][3] = __builtin_amdgcn_exp2f(e.w * LOG2E);
        }
#pragma unroll
        for (int ch = 0; ch < 4; ++ch) {
            Bf[ch][0] = pack2bf(x0[2 * ch][0],     x0[2 * ch][1]);
            Bf[ch][1] = pack2bf(x0[2 * ch][2],     x0[2 * ch][3]);
            Bf[ch][2] = pack2bf(x0[2 * ch + 1][0], x0[2 * ch + 1][1]);
            Bf[ch][3] = pack2bf(x0[2 * ch + 1][2], x0[2 * ch + 1][3]);
        }
    }

    // ---- prefetch t = 1..4 into 4 slots ----
    uint2  xbu[4][8];
    float4 xbf[4][8];
#pragma unroll
    for (int k = 0; k < 4; ++k)
#pragma unroll
        for (int jt = 0; jt < 8; ++jt) {
            if constexpr (XSP) xbu[k][jt] = xsu[8192 * (1 + k) + lb + 4 * jt];
            else               xbf[k][jt] = emf4[8192 * (1 + k) + lb + 4 * jt];
        }

    int ls2 = 0;
    float fin = 0.f;

    // ---- main loop: t = 1..508 (127 groups of 4), max-renorm on 4th ----
#pragma unroll 1
    for (int grp = 0; grp < 127; ++grp) {
        const int t0 = 1 + 4 * grp;
        STEP(0, t0 + 4, 1, 0, 0);
        STEP(1, t0 + 5, 1, 0, 0);
        STEP(2, t0 + 6, 1, 0, 0);
        STEP(3, t0 + 7, 1, 1, 0);
    }
    // tail: t = 509, 510, 511 (slots 0,1,2 hold them; growth fits fp32)
    STEP(0, 0, 0, 0, 0);
    STEP(1, 0, 0, 0, 0);
    STEP(2, 0, 0, 0, 1);

    // ---- finalize: combine the 4 g-lanes per batch ----
    fin += __shfl_xor(fin, 16);
    fin += __shfl_xor(fin, 32);
    if (l < 16)
        scan_part[gb * 16 + l] = ((float)ls2 + __log2f(fin)) * LN2F;
}

__global__ __launch_bounds__(256) void crf_gold_kernel(
    const float* __restrict__ emit, const float* __restrict__ Tm,
    const int* __restrict__ labels, const int* __restrict__ startp,
    float* __restrict__ gold_part)   // (256)
{
    const int b = blockIdx.x, tid = threadIdx.x;
    __shared__ int lab[512];
    __shared__ float r[4];
    lab[tid]       = labels[b * 512 + tid];
    lab[tid + 256] = labels[b * 512 + tid + 256];
    __syncthreads();
    float s = 0.f;
    {
        int y0 = lab[tid];
        int p0 = (tid == 0) ? startp[0] : lab[tid - 1];
        s += emit[((size_t)tid * 256 + b) * 128 + y0] + Tm[p0 * 128 + y0];
        int t1 = tid + 256;
        int y1 = lab[t1];
        int p1 = lab[t1 - 1];
        s += emit[((size_t)t1 * 256 + b) * 128 + y1] + Tm[p1 * 128 + y1];
    }
#pragma unroll
    for (int off = 1; off < 64; off <<= 1) s += __shfl_xor(s, off);
    if ((tid & 63) == 0) r[tid >> 6] = s;
    __syncthreads();
    if (tid == 0) gold_part[b] = (r[0] + r[1]) + (r[2] + r[3]);
}

__global__ __launch_bounds__(256) void crf_final_kernel(
    const float* __restrict__ scan_part, const float* __restrict__ gold_part,
    float* __restrict__ out)
{
    const int tid = threadIdx.x;
    __shared__ float r[4];
    float v = scan_part[tid] - gold_part[tid];
#pragma unroll
    for (int off = 1; off < 64; off <<= 1) v += __shfl_xor(v, off);
    if ((tid & 63) == 0) r[tid >> 6] = v;
    __syncthreads();
    if (tid == 0) out[0] = (r[0] + r[1]) + (r[2] + r[3]);
}

extern "C" void kernel_launch(void* const* d_in, const int* in_sizes, int n_in,
                              void* d_out, int out_size, void* d_ws, size_t ws_size,
                              hipStream_t stream) {
    const float* emit   = (const float*)d_in[0];
    const float* Tm     = (const float*)d_in[1];
    const int*   labels = (const int*)d_in[2];
    const int*   startp = (const int*)d_in[3];

    const size_t xs_bytes = (size_t)512 * 256 * 128 * 2;   // 33,554,432
    if (ws_size >= xs_bytes + 2048) {
        unsigned* xs        = (unsigned*)d_ws;
        float*    scan_part = (float*)((char*)d_ws + xs_bytes);
        float*    gold_part = scan_part + 256;
        crf_xs_kernel  <<<16384, 256, 0, stream>>>(emit, xs);
        crf_scan_kernel<true><<<16, 64, 0, stream>>>(emit, xs, Tm, scan_part);
        crf_gold_kernel<<<256, 256, 0, stream>>>(emit, Tm, labels, startp, gold_part);
        crf_final_kernel<<<1, 256, 0, stream>>>(scan_part, gold_part, (float*)d_out);
    } else {
        float* scan_part = (float*)d_ws;
        float* gold_part = scan_part + 256;
        crf_scan_kernel<false><<<16, 64, 0, stream>>>(emit, nullptr, Tm, scan_part);
        crf_gold_kernel<<<256, 256, 0, stream>>>(emit, Tm, labels, startp, gold_part);
        crf_final_kernel<<<1, 256, 0, stream>>>(scan_part, gold_part, (float*)d_out);
    }
}

// Round 6
// 271.996 us; speedup vs baseline: 1.4817x; 1.4817x over previous
//
#include <hip/hip_runtime.h>

// CRF loss, S=512, B=256, L=128; out = sum_b log_z_b - gold.
//
// Scan: one wave per 16 batches (16 blocks x 64 threads), ALL state in
// registers. Step t: D[j][b] = sum_k~ A[j][k~] * W~[k~][b] via 32x
// __builtin_amdgcn_mfma_f32_16x16x32_bf16 (8 j-tiles x 4 k-chunks), then
// w_new = D * xs, packed back to bf16 B-fragments IN-LANE (no LDS, no
// barriers, no cross-lane moves): the k-permutation pi baked into A makes
// the MFMA C/D register layout coincide with the B-fragment layout.
//   pi: j = 16jt + 4g + r  ->  k~ = 32*(jt>>1) + 8g + 4*(jt&1) + r
//   A[j][k~] = exp(T[pi^-1(k~)][j]),
//   pi^-1(32ch + 8g + e) = 32ch + 16*(e>>2) + 4g + (e&3).
// Layouts verified: R5 passed with absmax 0.0.
//
// R5 -> R6 perf fixes (R5 = 742 cyc/step, dependent-MFMA-latency bound):
//  1. ch-OUTER MFMA order: 8 independent MFMAs between dependent pairs
//     (issue-bound ~155 cyc) instead of jt-outer's 4-deep dependent chains
//     (latency-bound ~700 cyc).
//  2. Accumulator init folded into first MFMA (C = constant zero4): kills
//     32 v_mov zero-inits per step.
//  3. bf16 packing via native __bf16 casts -> compiler emits
//     v_cvt_pk_bf16_f32 (1 op / 2 values) instead of ~9-op manual RNE.
//
// Renorm every 4 steps by per-batch MAX exponent (exact power-of-2 scale,
// int ls2): after renorm values <= 2, growth <= ~2^14/step => fp32 safe.
//
// xs = exp(emit) precomputed as packed bf16 by a memory-bound full-GPU
// kernel into d_ws (33.5 MB); fallback computes exp2 in-scan if ws small.

#define LOG2E 1.4426950408889634f
#define LN2F  0.6931471805599453f

typedef float        f32x4  __attribute__((ext_vector_type(4)));
typedef unsigned int u32x4  __attribute__((ext_vector_type(4)));
typedef short        bf16x8 __attribute__((ext_vector_type(8)));
typedef __bf16       bf16x2 __attribute__((ext_vector_type(2)));

__device__ __forceinline__ unsigned packbf2(float lo, float hi) {
    bf16x2 p = { (__bf16)lo, (__bf16)hi };          // RNE; compiler -> v_cvt_pk_bf16_f32
    return __builtin_bit_cast(unsigned, p);
}
__device__ __forceinline__ float bflo(unsigned w) { return __uint_as_float(w << 16); }
__device__ __forceinline__ float bfhi(unsigned w) { return __uint_as_float(w & 0xFFFF0000u); }

#define MFMAB(Aop, Bop, Cop) \
    __builtin_amdgcn_mfma_f32_16x16x32_bf16( \
        __builtin_bit_cast(bf16x8, Aop), __builtin_bit_cast(bf16x8, Bop), Cop, 0, 0, 0)

// One scan step. SLOT: prefetch slot (literal). TPF: t to prefetch.
// DOPF/RN/LAST: literal flags. Uses kernel scope: Afr, Bf, zero4, xbu, xbf,
// xsu, emf4, lb, ls2, fin.
#define STEP(SLOT, TPF, DOPF, RN, LAST) do {                                  \
    f32x4 ac[8];                                                              \
    _Pragma("unroll") for (int jt = 0; jt < 8; ++jt)                          \
        ac[jt] = MFMAB(Afr[0][jt], Bf[0], zero4);                             \
    _Pragma("unroll") for (int ch = 1; ch < 4; ++ch)                          \
        _Pragma("unroll") for (int jt = 0; jt < 8; ++jt)                      \
            ac[jt] = MFMAB(Afr[ch][jt], Bf[ch], ac[jt]);                      \
    float xv[8][4];                                                           \
    if constexpr (XSP) {                                                      \
        _Pragma("unroll") for (int jt = 0; jt < 8; ++jt) {                    \
            uint2 xw = xbu[SLOT][jt];                                         \
            xv[jt][0] = bflo(xw.x); xv[jt][1] = bfhi(xw.x);                   \
            xv[jt][2] = bflo(xw.y); xv[jt][3] = bfhi(xw.y);                   \
        }                                                                     \
    } else {                                                                  \
        _Pragma("unroll") for (int jt = 0; jt < 8; ++jt) {                    \
            float4 xw = xbf[SLOT][jt];                                        \
            xv[jt][0] = __builtin_amdgcn_exp2f(xw.x * LOG2E);                 \
            xv[jt][1] = __builtin_amdgcn_exp2f(xw.y * LOG2E);                 \
            xv[jt][2] = __builtin_amdgcn_exp2f(xw.z * LOG2E);                 \
            xv[jt][3] = __builtin_amdgcn_exp2f(xw.w * LOG2E);                 \
        }                                                                     \
    }                                                                         \
    if (DOPF) {                                                               \
        int tp = (TPF); if (tp > 511) tp = 511;                               \
        if constexpr (XSP) {                                                  \
            _Pragma("unroll") for (int jt = 0; jt < 8; ++jt)                  \
                xbu[SLOT][jt] = xsu[8192 * tp + lb + 4 * jt];                 \
        } else {                                                              \
            _Pragma("unroll") for (int jt = 0; jt < 8; ++jt)                  \
                xbf[SLOT][jt] = emf4[8192 * tp + lb + 4 * jt];                \
        }                                                                     \
    }                                                                         \
    float vv[8][4];                                                           \
    _Pragma("unroll") for (int jt = 0; jt < 8; ++jt)                          \
        _Pragma("unroll") for (int r = 0; r < 4; ++r)                         \
            vv[jt][r] = ac[jt][r] * xv[jt][r];                                \
    if (RN) {                                                                 \
        float mx = vv[0][0];                                                  \
        _Pragma("unroll") for (int jt = 0; jt < 8; ++jt)                      \
            _Pragma("unroll") for (int r = 0; r < 4; ++r)                     \
                mx = fmaxf(mx, vv[jt][r]);                                    \
        mx = fmaxf(mx, __shfl_xor(mx, 16));                                   \
        mx = fmaxf(mx, __shfl_xor(mx, 32));                                   \
        int Ee = (__float_as_int(mx) >> 23) & 0xFF;                           \
        if (Ee > 254) Ee = 254;                                               \
        ls2 += Ee - 127;                                                      \
        float scl = __int_as_float((254 - Ee) << 23);                         \
        _Pragma("unroll") for (int jt = 0; jt < 8; ++jt)                      \
            _Pragma("unroll") for (int r = 0; r < 4; ++r)                     \
                vv[jt][r] *= scl;                                             \
    }                                                                         \
    if (LAST) {                                                               \
        fin = 0.f;                                                            \
        _Pragma("unroll") for (int jt = 0; jt < 8; ++jt)                      \
            fin += (vv[jt][0] + vv[jt][1]) + (vv[jt][2] + vv[jt][3]);         \
    } else {                                                                  \
        _Pragma("unroll") for (int ch = 0; ch < 4; ++ch) {                    \
            Bf[ch][0] = packbf2(vv[2*ch][0],     vv[2*ch][1]);                \
            Bf[ch][1] = packbf2(vv[2*ch][2],     vv[2*ch][3]);                \
            Bf[ch][2] = packbf2(vv[2*ch + 1][0], vv[2*ch + 1][1]);            \
            Bf[ch][3] = packbf2(vv[2*ch + 1][2], vv[2*ch + 1][3]);            \
        }                                                                     \
    }                                                                         \
} while (0)

// xs[t][b][j] = exp(emit[t][b][j]) as packed bf16 (memory-bound, full GPU).
__global__ __launch_bounds__(256) void crf_xs_kernel(
    const float* __restrict__ emit, unsigned* __restrict__ xs)
{
    const size_t i = (size_t)blockIdx.x * 256 + threadIdx.x;  // uint2 index
    const float4 e = ((const float4*)emit)[i];
    uint2 o;
    o.x = packbf2(__builtin_amdgcn_exp2f(e.x * LOG2E),
                  __builtin_amdgcn_exp2f(e.y * LOG2E));
    o.y = packbf2(__builtin_amdgcn_exp2f(e.z * LOG2E),
                  __builtin_amdgcn_exp2f(e.w * LOG2E));
    ((uint2*)xs)[i] = o;
}

template<bool XSP>
__global__ __launch_bounds__(64, 1) void crf_scan_kernel(
    const float* __restrict__ emit,
    const unsigned* __restrict__ xs,
    const float* __restrict__ Tm,
    float* __restrict__ scan_part)   // (256)
{
    const int gb = blockIdx.x;       // batch group 0..15
    const int l  = threadIdx.x;      // 0..63
    const int b  = l & 15;           // batch within group (MFMA m/n index)
    const int g  = l >> 4;           // 16-lane group
    const int bg = gb * 16 + b;
    const int lb = 32 * bg + g;      // per-lane uint2/float4 base index

    const uint2*  xsu  = (const uint2*)xs;
    const float4* emf4 = (const float4*)emit;
    const f32x4 zero4 = {0.f, 0.f, 0.f, 0.f};

    // ---- constant A fragments: lane holds A[m = l&15][k = 8g + e] ----
    // A[j][k~] = exp(T[pi^-1(k~)][j]), j = 16jt + (l&15),
    // pi^-1(32ch + 8g + e) = 32ch + 16*(e>>2) + 4g + (e&3).
    u32x4 Afr[4][8];
#pragma unroll
    for (int ch = 0; ch < 4; ++ch)
#pragma unroll
        for (int p = 0; p < 4; ++p) {
            const int e0 = 2 * p, e1 = 2 * p + 1;
            const int jp0 = 32 * ch + 16 * (e0 >> 2) + 4 * g + (e0 & 3);
            const int jp1 = 32 * ch + 16 * (e1 >> 2) + 4 * g + (e1 & 3);
#pragma unroll
            for (int jt = 0; jt < 8; ++jt) {
                float a0 = __builtin_amdgcn_exp2f(Tm[jp0 * 128 + 16 * jt + b] * LOG2E);
                float a1 = __builtin_amdgcn_exp2f(Tm[jp1 * 128 + 16 * jt + b] * LOG2E);
                Afr[ch][jt][p] = packbf2(a0, a1);
            }
        }

    // ---- t=0 init: B-frags = xs[0] (w0 = exp(emit[0])), pi-packed ----
    u32x4 Bf[4];
    if constexpr (XSP) {
        uint2 tw[8];
#pragma unroll
        for (int jt = 0; jt < 8; ++jt) tw[jt] = xsu[lb + 4 * jt];
#pragma unroll
        for (int ch = 0; ch < 4; ++ch) {
            Bf[ch][0] = tw[2 * ch].x;     Bf[ch][1] = tw[2 * ch].y;
            Bf[ch][2] = tw[2 * ch + 1].x; Bf[ch][3] = tw[2 * ch + 1].y;
        }
    } else {
        float x0[8][4];
#pragma unroll
        for (int jt = 0; jt < 8; ++jt) {
            float4 e = emf4[lb + 4 * jt];
            x0[jt][0] = __builtin_amdgcn_exp2f(e.x * LOG2E);
            x0[jt][1] = __builtin_amdgcn_exp2f(e.y * LOG2E);
            x0[jt][2] = __builtin_amdgcn_exp2f(e.z * LOG2E);
            x0[jt][3] = __builtin_amdgcn_exp2f(e.w * LOG2E);
        }
#pragma unroll
        for (int ch = 0; ch < 4; ++ch) {
            Bf[ch][0] = packbf2(x0[2 * ch][0],     x0[2 * ch][1]);
            Bf[ch][1] = packbf2(x0[2 * ch][2],     x0[2 * ch][3]);
            Bf[ch][2] = packbf2(x0[2 * ch + 1][0], x0[2 * ch + 1][1]);
            Bf[ch][3] = packbf2(x0[2 * ch + 1][2], x0[2 * ch + 1][3]);
        }
    }

    // ---- prefetch t = 1..4 into 4 slots ----
    uint2  xbu[4][8];
    float4 xbf[4][8];
#pragma unroll
    for (int k = 0; k < 4; ++k)
#pragma unroll
        for (int jt = 0; jt < 8; ++jt) {
            if constexpr (XSP) xbu[k][jt] = xsu[8192 * (1 + k) + lb + 4 * jt];
            else               xbf[k][jt] = emf4[8192 * (1 + k) + lb + 4 * jt];
        }

    int ls2 = 0;
    float fin = 0.f;

    // ---- main loop: t = 1..508 (127 groups of 4), max-renorm on 4th ----
#pragma unroll 1
    for (int grp = 0; grp < 127; ++grp) {
        const int t0 = 1 + 4 * grp;
        STEP(0, t0 + 4, 1, 0, 0);
        STEP(1, t0 + 5, 1, 0, 0);
        STEP(2, t0 + 6, 1, 0, 0);
        STEP(3, t0 + 7, 1, 1, 0);
    }
    // tail: t = 509, 510, 511 (slots 0,1,2 hold them; growth fits fp32)
    STEP(0, 0, 0, 0, 0);
    STEP(1, 0, 0, 0, 0);
    STEP(2, 0, 0, 0, 1);

    // ---- finalize: combine the 4 g-lanes per batch ----
    fin += __shfl_xor(fin, 16);
    fin += __shfl_xor(fin, 32);
    if (l < 16)
        scan_part[gb * 16 + l] = ((float)ls2 + __log2f(fin)) * LN2F;
}

__global__ __launch_bounds__(256) void crf_gold_kernel(
    const float* __restrict__ emit, const float* __restrict__ Tm,
    const int* __restrict__ labels, const int* __restrict__ startp,
    float* __restrict__ gold_part)   // (256)
{
    const int b = blockIdx.x, tid = threadIdx.x;
    __shared__ int lab[512];
    __shared__ float r[4];
    lab[tid]       = labels[b * 512 + tid];
    lab[tid + 256] = labels[b * 512 + tid + 256];
    __syncthreads();
    float s = 0.f;
    {
        int y0 = lab[tid];
        int p0 = (tid == 0) ? startp[0] : lab[tid - 1];
        s += emit[((size_t)tid * 256 + b) * 128 + y0] + Tm[p0 * 128 + y0];
        int t1 = tid + 256;
        int y1 = lab[t1];
        int p1 = lab[t1 - 1];
        s += emit[((size_t)t1 * 256 + b) * 128 + y1] + Tm[p1 * 128 + y1];
    }
#pragma unroll
    for (int off = 1; off < 64; off <<= 1) s += __shfl_xor(s, off);
    if ((tid & 63) == 0) r[tid >> 6] = s;
    __syncthreads();
    if (tid == 0) gold_part[b] = (r[0] + r[1]) + (r[2] + r[3]);
}

__global__ __launch_bounds__(256) void crf_final_kernel(
    const float* __restrict__ scan_part, const float* __restrict__ gold_part,
    float* __restrict__ out)
{
    const int tid = threadIdx.x;
    __shared__ float r[4];
    float v = scan_part[tid] - gold_part[tid];
#pragma unroll
    for (int off = 1; off < 64; off <<= 1) v += __shfl_xor(v, off);
    if ((tid & 63) == 0) r[tid >> 6] = v;
    __syncthreads();
    if (tid == 0) out[0] = (r[0] + r[1]) + (r[2] + r[3]);
}

extern "C" void kernel_launch(void* const* d_in, const int* in_sizes, int n_in,
                              void* d_out, int out_size, void* d_ws, size_t ws_size,
                              hipStream_t stream) {
    const float* emit   = (const float*)d_in[0];
    const float* Tm     = (const float*)d_in[1];
    const int*   labels = (const int*)d_in[2];
    const int*   startp = (const int*)d_in[3];

    const size_t xs_bytes = (size_t)512 * 256 * 128 * 2;   // 33,554,432
    if (ws_size >= xs_bytes + 2048) {
        unsigned* xs        = (unsigned*)d_ws;
        float*    scan_part = (float*)((char*)d_ws + xs_bytes);
        float*    gold_part = scan_part + 256;
        crf_xs_kernel  <<<16384, 256, 0, stream>>>(emit, xs);
        crf_scan_kernel<true><<<16, 64, 0, stream>>>(emit, xs, Tm, scan_part);
        crf_gold_kernel<<<256, 256, 0, stream>>>(emit, Tm, labels, startp, gold_part);
        crf_final_kernel<<<1, 256, 0, stream>>>(scan_part, gold_part, (float*)d_out);
    } else {
        float* scan_part = (float*)d_ws;
        float* gold_part = scan_part + 256;
        crf_scan_kernel<false><<<16, 64, 0, stream>>>(emit, nullptr, Tm, scan_part);
        crf_gold_kernel<<<256, 256, 0, stream>>>(emit, Tm, labels, startp, gold_part);
        crf_final_kernel<<<1, 256, 0, stream>>>(scan_part, gold_part, (float*)d_out);
    }
}

// Round 7
// 254.621 us; speedup vs baseline: 1.5828x; 1.0682x over previous
//
#include <hip/hip_runtime.h>

// CRF loss, S=512, B=256, L=128; out = sum_b log_z_b - gold.
//
// Scan: one wave per 16 batches (16 blocks x 64 threads), ALL state in
// registers. Step t: D[j][b] = sum_k~ A[j][k~] * W~[k~][b] via 32x
// __builtin_amdgcn_mfma_f32_16x16x32_bf16 (ch-outer: 8 independent MFMAs
// between dependent pairs), then w_new = D * xs, packed to bf16 B-frags
// IN-LANE (no LDS / barriers / cross-lane): k-permutation pi baked into A
// makes the MFMA C/D register layout coincide with the B-fragment layout.
//   pi: j = 16jt + 4g + r  ->  k~ = 32*(jt>>1) + 8g + 4*(jt&1) + r
//   A[j][k~] = exp(T[pi^-1(k~)][j]),
//   pi^-1(32ch + 8g + e) = 32ch + 16*(e>>2) + 4g + (e&3).
// Layouts verified: R5/R6 passed with absmax 0.0.
//
// R6 -> R7 (R6 = 489 cyc/step, single-wave issue-serialization bound):
//  1. xs precomputed as FP32 (67 MB in d_ws): float4 loads ARE the multiply
//     operands — kills 32 bf16-extract VALU ops/step (64 cyc of issue).
//  2. Renorm every 8 steps (growth <= 2^14.4/step; 8 steps from <=2 stays
//     < 2^117, shrink floor ~2^-52 — fp32-safe): renorm tax 14 -> 9 cyc.
//  MODE: 0 = fp32 xs, 1 = bf16 xs (ws medium), 2 = exp2-in-scan (ws tiny).

#define LOG2E 1.4426950408889634f
#define LN2F  0.6931471805599453f

typedef float        f32x4  __attribute__((ext_vector_type(4)));
typedef unsigned int u32x4  __attribute__((ext_vector_type(4)));
typedef short        bf16x8 __attribute__((ext_vector_type(8)));
typedef __bf16       bf16x2 __attribute__((ext_vector_type(2)));

__device__ __forceinline__ unsigned packbf2(float lo, float hi) {
    bf16x2 p = { (__bf16)lo, (__bf16)hi };   // RNE; compiler -> v_cvt_pk_bf16_f32
    return __builtin_bit_cast(unsigned, p);
}
__device__ __forceinline__ float bflo(unsigned w) { return __uint_as_float(w << 16); }
__device__ __forceinline__ float bfhi(unsigned w) { return __uint_as_float(w & 0xFFFF0000u); }

#define MFMAB(Aop, Bop, Cop) \
    __builtin_amdgcn_mfma_f32_16x16x32_bf16( \
        __builtin_bit_cast(bf16x8, Aop), __builtin_bit_cast(bf16x8, Bop), Cop, 0, 0, 0)

// One scan step. SLOT/TPF/DOPF/RN/LAST are literals. Kernel scope: Afr, Bf,
// zero4, xf, xbu, xbf, xsf, xsu, emf4, lb, ls2, fin.
#define STEP(SLOT, TPF, DOPF, RN, LAST) do {                                  \
    f32x4 ac[8];                                                              \
    _Pragma("unroll") for (int jt = 0; jt < 8; ++jt)                          \
        ac[jt] = MFMAB(Afr[0][jt], Bf[0], zero4);                             \
    _Pragma("unroll") for (int ch = 1; ch < 4; ++ch)                          \
        _Pragma("unroll") for (int jt = 0; jt < 8; ++jt)                      \
            ac[jt] = MFMAB(Afr[ch][jt], Bf[ch], ac[jt]);                      \
    float xv[8][4];                                                           \
    if constexpr (MODE == 0) {                                                \
        _Pragma("unroll") for (int jt = 0; jt < 8; ++jt) {                    \
            f32x4 xw = xf[SLOT][jt];                                          \
            xv[jt][0] = xw[0]; xv[jt][1] = xw[1];                             \
            xv[jt][2] = xw[2]; xv[jt][3] = xw[3];                             \
        }                                                                     \
    } else if constexpr (MODE == 1) {                                         \
        _Pragma("unroll") for (int jt = 0; jt < 8; ++jt) {                    \
            uint2 xw = xbu[SLOT][jt];                                         \
            xv[jt][0] = bflo(xw.x); xv[jt][1] = bfhi(xw.x);                   \
            xv[jt][2] = bflo(xw.y); xv[jt][3] = bfhi(xw.y);                   \
        }                                                                     \
    } else {                                                                  \
        _Pragma("unroll") for (int jt = 0; jt < 8; ++jt) {                    \
            float4 xw = xbf[SLOT][jt];                                        \
            xv[jt][0] = __builtin_amdgcn_exp2f(xw.x * LOG2E);                 \
            xv[jt][1] = __builtin_amdgcn_exp2f(xw.y * LOG2E);                 \
            xv[jt][2] = __builtin_amdgcn_exp2f(xw.z * LOG2E);                 \
            xv[jt][3] = __builtin_amdgcn_exp2f(xw.w * LOG2E);                 \
        }                                                                     \
    }                                                                         \
    if (DOPF) {                                                               \
        int tp = (TPF); if (tp > 511) tp = 511;                               \
        if constexpr (MODE == 0) {                                            \
            _Pragma("unroll") for (int jt = 0; jt < 8; ++jt)                  \
                xf[SLOT][jt] = xsf[8192 * tp + lb + 4 * jt];                  \
        } else if constexpr (MODE == 1) {                                     \
            _Pragma("unroll") for (int jt = 0; jt < 8; ++jt)                  \
                xbu[SLOT][jt] = xsu[8192 * tp + lb + 4 * jt];                 \
        } else {                                                              \
            _Pragma("unroll") for (int jt = 0; jt < 8; ++jt)                  \
                xbf[SLOT][jt] = emf4[8192 * tp + lb + 4 * jt];                \
        }                                                                     \
    }                                                                         \
    float vv[8][4];                                                           \
    _Pragma("unroll") for (int jt = 0; jt < 8; ++jt)                          \
        _Pragma("unroll") for (int r = 0; r < 4; ++r)                         \
            vv[jt][r] = ac[jt][r] * xv[jt][r];                                \
    if (RN) {                                                                 \
        float mx = vv[0][0];                                                  \
        _Pragma("unroll") for (int jt = 0; jt < 8; ++jt)                      \
            _Pragma("unroll") for (int r = 0; r < 4; ++r)                     \
                mx = fmaxf(mx, vv[jt][r]);                                    \
        mx = fmaxf(mx, __shfl_xor(mx, 16));                                   \
        mx = fmaxf(mx, __shfl_xor(mx, 32));                                   \
        int Ee = (__float_as_int(mx) >> 23) & 0xFF;                           \
        if (Ee > 254) Ee = 254;                                               \
        ls2 += Ee - 127;                                                      \
        float scl = __int_as_float((254 - Ee) << 23);                         \
        _Pragma("unroll") for (int jt = 0; jt < 8; ++jt)                      \
            _Pragma("unroll") for (int r = 0; r < 4; ++r)                     \
                vv[jt][r] *= scl;                                             \
    }                                                                         \
    if (LAST) {                                                               \
        fin = 0.f;                                                            \
        _Pragma("unroll") for (int jt = 0; jt < 8; ++jt)                      \
            fin += (vv[jt][0] + vv[jt][1]) + (vv[jt][2] + vv[jt][3]);         \
    } else {                                                                  \
        _Pragma("unroll") for (int ch = 0; ch < 4; ++ch) {                    \
            Bf[ch][0] = packbf2(vv[2*ch][0],     vv[2*ch][1]);                \
            Bf[ch][1] = packbf2(vv[2*ch][2],     vv[2*ch][3]);                \
            Bf[ch][2] = packbf2(vv[2*ch + 1][0], vv[2*ch + 1][1]);            \
            Bf[ch][3] = packbf2(vv[2*ch + 1][2], vv[2*ch + 1][3]);            \
        }                                                                     \
    }                                                                         \
} while (0)

// xs = exp(emit), fp32 (memory-bound, full GPU).
__global__ __launch_bounds__(256) void crf_xs32_kernel(
    const float* __restrict__ emit, float* __restrict__ xs)
{
    const size_t i = (size_t)blockIdx.x * 256 + threadIdx.x;  // float4 index
    const float4 e = ((const float4*)emit)[i];
    float4 o;
    o.x = __builtin_amdgcn_exp2f(e.x * LOG2E);
    o.y = __builtin_amdgcn_exp2f(e.y * LOG2E);
    o.z = __builtin_amdgcn_exp2f(e.z * LOG2E);
    o.w = __builtin_amdgcn_exp2f(e.w * LOG2E);
    ((float4*)xs)[i] = o;
}

// xs = exp(emit), packed bf16 (fallback for medium ws).
__global__ __launch_bounds__(256) void crf_xs16_kernel(
    const float* __restrict__ emit, unsigned* __restrict__ xs)
{
    const size_t i = (size_t)blockIdx.x * 256 + threadIdx.x;  // uint2 index
    const float4 e = ((const float4*)emit)[i];
    uint2 o;
    o.x = packbf2(__builtin_amdgcn_exp2f(e.x * LOG2E),
                  __builtin_amdgcn_exp2f(e.y * LOG2E));
    o.y = packbf2(__builtin_amdgcn_exp2f(e.z * LOG2E),
                  __builtin_amdgcn_exp2f(e.w * LOG2E));
    ((uint2*)xs)[i] = o;
}

template<int MODE>
__global__ __launch_bounds__(64, 1) void crf_scan_kernel(
    const float* __restrict__ emit,
    const void* __restrict__ xs,
    const float* __restrict__ Tm,
    float* __restrict__ scan_part)   // (256)
{
    const int gb = blockIdx.x;       // batch group 0..15
    const int l  = threadIdx.x;      // 0..63
    const int b  = l & 15;           // batch within group (MFMA m/n index)
    const int g  = l >> 4;           // 16-lane group
    const int bg = gb * 16 + b;
    const int lb = 32 * bg + g;      // per-lane float4/uint2 base index

    const f32x4*  xsf  = (const f32x4*)xs;
    const uint2*  xsu  = (const uint2*)xs;
    const float4* emf4 = (const float4*)emit;
    const f32x4 zero4 = {0.f, 0.f, 0.f, 0.f};

    // ---- constant A fragments: lane holds A[m = l&15][k = 8g + e] ----
    u32x4 Afr[4][8];
#pragma unroll
    for (int ch = 0; ch < 4; ++ch)
#pragma unroll
        for (int p = 0; p < 4; ++p) {
            const int e0 = 2 * p, e1 = 2 * p + 1;
            const int jp0 = 32 * ch + 16 * (e0 >> 2) + 4 * g + (e0 & 3);
            const int jp1 = 32 * ch + 16 * (e1 >> 2) + 4 * g + (e1 & 3);
#pragma unroll
            for (int jt = 0; jt < 8; ++jt) {
                float a0 = __builtin_amdgcn_exp2f(Tm[jp0 * 128 + 16 * jt + b] * LOG2E);
                float a1 = __builtin_amdgcn_exp2f(Tm[jp1 * 128 + 16 * jt + b] * LOG2E);
                Afr[ch][jt][p] = packbf2(a0, a1);
            }
        }

    // ---- t=0 init: B-frags = exp(emit[0]), pi-packed ----
    u32x4 Bf[4];
    {
        float x0[8][4];
#pragma unroll
        for (int jt = 0; jt < 8; ++jt) {
            float4 e = emf4[lb + 4 * jt];
            x0[jt][0] = __builtin_amdgcn_exp2f(e.x * LOG2E);
            x0[jt][1] = __builtin_amdgcn_exp2f(e.y * LOG2E);
            x0[jt][2] = __builtin_amdgcn_exp2f(e.z * LOG2E);
            x0[jt][3] = __builtin_amdgcn_exp2f(e.w * LOG2E);
        }
#pragma unroll
        for (int ch = 0; ch < 4; ++ch) {
            Bf[ch][0] = packbf2(x0[2 * ch][0],     x0[2 * ch][1]);
            Bf[ch][1] = packbf2(x0[2 * ch][2],     x0[2 * ch][3]);
            Bf[ch][2] = packbf2(x0[2 * ch + 1][0], x0[2 * ch + 1][1]);
            Bf[ch][3] = packbf2(x0[2 * ch + 1][2], x0[2 * ch + 1][3]);
        }
    }

    // ---- prefetch t = 1..4 into 4 slots ----
    f32x4  xf [4][8];
    uint2  xbu[4][8];
    float4 xbf[4][8];
#pragma unroll
    for (int k = 0; k < 4; ++k)
#pragma unroll
        for (int jt = 0; jt < 8; ++jt) {
            if constexpr (MODE == 0)      xf [k][jt] = xsf [8192 * (1 + k) + lb + 4 * jt];
            else if constexpr (MODE == 1) xbu[k][jt] = xsu [8192 * (1 + k) + lb + 4 * jt];
            else                          xbf[k][jt] = emf4[8192 * (1 + k) + lb + 4 * jt];
        }

    int ls2 = 0;
    float fin = 0.f;

    // ---- main loop: t = 1..504 (63 groups of 8), max-renorm on 8th ----
#pragma unroll 1
    for (int grp = 0; grp < 63; ++grp) {
        const int t0 = 1 + 8 * grp;
        STEP(0, t0 + 4,  1, 0, 0);
        STEP(1, t0 + 5,  1, 0, 0);
        STEP(2, t0 + 6,  1, 0, 0);
        STEP(3, t0 + 7,  1, 0, 0);
        STEP(0, t0 + 8,  1, 0, 0);
        STEP(1, t0 + 9,  1, 0, 0);
        STEP(2, t0 + 10, 1, 0, 0);
        STEP(3, t0 + 11, 1, 1, 0);
    }
    // tail: t = 505..511 (slots hold 505..508; growth over 7 steps fp32-safe)
    STEP(0, 509, 1, 0, 0);   // t=505
    STEP(1, 510, 1, 0, 0);   // t=506
    STEP(2, 511, 1, 0, 0);   // t=507
    STEP(3, 0,   0, 0, 0);   // t=508
    STEP(0, 0,   0, 0, 0);   // t=509
    STEP(1, 0,   0, 0, 0);   // t=510
    STEP(2, 0,   0, 0, 1);   // t=511

    // ---- finalize: combine the 4 g-lanes per batch ----
    fin += __shfl_xor(fin, 16);
    fin += __shfl_xor(fin, 32);
    if (l < 16)
        scan_part[gb * 16 + l] = ((float)ls2 + __log2f(fin)) * LN2F;
}

__global__ __launch_bounds__(256) void crf_gold_kernel(
    const float* __restrict__ emit, const float* __restrict__ Tm,
    const int* __restrict__ labels, const int* __restrict__ startp,
    float* __restrict__ gold_part)   // (256)
{
    const int b = blockIdx.x, tid = threadIdx.x;
    __shared__ int lab[512];
    __shared__ float r[4];
    lab[tid]       = labels[b * 512 + tid];
    lab[tid + 256] = labels[b * 512 + tid + 256];
    __syncthreads();
    float s = 0.f;
    {
        int y0 = lab[tid];
        int p0 = (tid == 0) ? startp[0] : lab[tid - 1];
        s += emit[((size_t)tid * 256 + b) * 128 + y0] + Tm[p0 * 128 + y0];
        int t1 = tid + 256;
        int y1 = lab[t1];
        int p1 = lab[t1 - 1];
        s += emit[((size_t)t1 * 256 + b) * 128 + y1] + Tm[p1 * 128 + y1];
    }
#pragma unroll
    for (int off = 1; off < 64; off <<= 1) s += __shfl_xor(s, off);
    if ((tid & 63) == 0) r[tid >> 6] = s;
    __syncthreads();
    if (tid == 0) gold_part[b] = (r[0] + r[1]) + (r[2] + r[3]);
}

__global__ __launch_bounds__(256) void crf_final_kernel(
    const float* __restrict__ scan_part, const float* __restrict__ gold_part,
    float* __restrict__ out)
{
    const int tid = threadIdx.x;
    __shared__ float r[4];
    float v = scan_part[tid] - gold_part[tid];
#pragma unroll
    for (int off = 1; off < 64; off <<= 1) v += __shfl_xor(v, off);
    if ((tid & 63) == 0) r[tid >> 6] = v;
    __syncthreads();
    if (tid == 0) out[0] = (r[0] + r[1]) + (r[2] + r[3]);
}

extern "C" void kernel_launch(void* const* d_in, const int* in_sizes, int n_in,
                              void* d_out, int out_size, void* d_ws, size_t ws_size,
                              hipStream_t stream) {
    const float* emit   = (const float*)d_in[0];
    const float* Tm     = (const float*)d_in[1];
    const int*   labels = (const int*)d_in[2];
    const int*   startp = (const int*)d_in[3];

    const size_t xs32_bytes = (size_t)512 * 256 * 128 * 4;   // 67,108,864
    const size_t xs16_bytes = (size_t)512 * 256 * 128 * 2;   // 33,554,432

    if (ws_size >= xs32_bytes + 2048) {
        float* xs        = (float*)d_ws;
        float* scan_part = (float*)((char*)d_ws + xs32_bytes);
        float* gold_part = scan_part + 256;
        crf_xs32_kernel<<<16384, 256, 0, stream>>>(emit, xs);
        crf_scan_kernel<0><<<16, 64, 0, stream>>>(emit, xs, Tm, scan_part);
        crf_gold_kernel<<<256, 256, 0, stream>>>(emit, Tm, labels, startp, gold_part);
        crf_final_kernel<<<1, 256, 0, stream>>>(scan_part, gold_part, (float*)d_out);
    } else if (ws_size >= xs16_bytes + 2048) {
        unsigned* xs     = (unsigned*)d_ws;
        float* scan_part = (float*)((char*)d_ws + xs16_bytes);
        float* gold_part = scan_part + 256;
        crf_xs16_kernel<<<16384, 256, 0, stream>>>(emit, xs);
        crf_scan_kernel<1><<<16, 64, 0, stream>>>(emit, xs, Tm, scan_part);
        crf_gold_kernel<<<256, 256, 0, stream>>>(emit, Tm, labels, startp, gold_part);
        crf_final_kernel<<<1, 256, 0, stream>>>(scan_part, gold_part, (float*)d_out);
    } else {
        float* scan_part = (float*)d_ws;
        float* gold_part = scan_part + 256;
        crf_scan_kernel<2><<<16, 64, 0, stream>>>(emit, nullptr, Tm, scan_part);
        crf_gold_kernel<<<256, 256, 0, stream>>>(emit, Tm, labels, startp, gold_part);
        crf_final_kernel<<<1, 256, 0, stream>>>(scan_part, gold_part, (float*)d_out);
    }
}

// Round 8
// 226.252 us; speedup vs baseline: 1.7813x; 1.1254x over previous
//
#include <hip/hip_runtime.h>

// CRF loss, S=512, B=256, L=128; out = sum_b log_z_b - gold.
//
// R8: scan step via MX-scaled fp8 MFMA: 8x mfma_scale_f32_16x16x128_f8f6f4
// (K=128 in ONE instruction, all 8 independent) replaces 32x bf16 16x16x32.
// A = exp(T)^T permuted, e4m3 (cbsz=0), constant in regs (64 VGPR). W state =
// raw f32 step output stored as e5m2 bytes (blgp=1); the per-step power-of-2
// renorm is applied via the MFMA's B-scale operand (e8m0 byte = 252 - Ee,
// scale = 2^(125-Ee)), zero data-path VALU. ls2 accumulates applied exps.
//
//   B byte layout (lane l: b = l&15, g = l>>4): byte e = 4d+c of dword d
//     holds k~ = 32g + 4d + c.
//   D tile d reg r holds j = 16d + 4g + r -> stored at byte 4d + r, so
//     pi: j = 16d + 4g + r <-> k~ = 32g + 4d + r, pi^-1(32g+4d+c) = 16d+4g+c.
//   A[j'][k~] = exp(T[pi^-1(k~)][j']).
//
// Range (e5m2 max 57344 = 2^15.8): scaled prev max in [0.25,0.5) => ac <=
// 0.5*128*1.65 ~ 105; vv = ac*xs <= 105*244 ~ 2^14.6 < max. Flush floor
// 2^-16 abs (<= 2^-14 rel to max): negligible dropped mass.
//
// xs = exp(emit) precomputed fp32 (67 MB in d_ws); bf16 in-scan fallback
// (R7's verified structure) if ws is too small.

#define LOG2E 1.4426950408889634f
#define LN2F  0.6931471805599453f

typedef float        f32x4  __attribute__((ext_vector_type(4)));
typedef int          i32x8  __attribute__((ext_vector_type(8)));
typedef unsigned int u32x4  __attribute__((ext_vector_type(4)));
typedef short        bf16x8 __attribute__((ext_vector_type(8)));
typedef __bf16       bf16x2 __attribute__((ext_vector_type(2)));

__device__ __forceinline__ unsigned packbf2(float lo, float hi) {
    bf16x2 p = { (__bf16)lo, (__bf16)hi };   // RNE; compiler -> v_cvt_pk_bf16_f32
    return __builtin_bit_cast(unsigned, p);
}

// ---------------- MX fp8 scan step ----------------
// Kernel scope: Afr, Bq, sclw, zero4, xf, xsf, lb, ls2, fin.
#define STEPX(SLOT, TPF, DOPF, LAST) do {                                     \
    f32x4 ac[8];                                                              \
    _Pragma("unroll") for (int jt = 0; jt < 8; ++jt)                          \
        ac[jt] = __builtin_amdgcn_mfma_scale_f32_16x16x128_f8f6f4(            \
            Afr[jt], Bq, zero4, 0, 1, 0, 0x7F7F7F7F, 0, sclw);                \
    float vv[8][4];                                                           \
    _Pragma("unroll") for (int jt = 0; jt < 8; ++jt) {                        \
        f32x4 xw = xf[SLOT][jt];                                              \
        vv[jt][0] = ac[jt][0] * xw[0];                                        \
        vv[jt][1] = ac[jt][1] * xw[1];                                        \
        vv[jt][2] = ac[jt][2] * xw[2];                                        \
        vv[jt][3] = ac[jt][3] * xw[3];                                        \
    }                                                                         \
    if (DOPF) {                                                               \
        int tp = (TPF); if (tp > 511) tp = 511;                               \
        _Pragma("unroll") for (int jt = 0; jt < 8; ++jt)                      \
            xf[SLOT][jt] = xsf[8192 * tp + lb + 4 * jt];                      \
    }                                                                         \
    if (LAST) {                                                               \
        fin = 0.f;                                                            \
        _Pragma("unroll") for (int jt = 0; jt < 8; ++jt)                      \
            fin += (vv[jt][0] + vv[jt][1]) + (vv[jt][2] + vv[jt][3]);         \
    } else {                                                                  \
        float m8[8];                                                          \
        _Pragma("unroll") for (int jt = 0; jt < 8; ++jt)                      \
            m8[jt] = fmaxf(fmaxf(vv[jt][0], vv[jt][1]),                       \
                           fmaxf(vv[jt][2], vv[jt][3]));                      \
        float mx = fmaxf(fmaxf(fmaxf(m8[0], m8[1]), fmaxf(m8[2], m8[3])),     \
                         fmaxf(fmaxf(m8[4], m8[5]), fmaxf(m8[6], m8[7])));    \
        mx = fmaxf(mx, __shfl_xor(mx, 16));                                   \
        mx = fmaxf(mx, __shfl_xor(mx, 32));                                   \
        int Ee = (__float_as_int(mx) >> 23) & 0xFF;                           \
        if (Ee < 16)  Ee = 16;                                                \
        if (Ee > 250) Ee = 250;                                               \
        ls2 += Ee - 125;                                                      \
        sclw = (252 - Ee) * 0x01010101;                                       \
        _Pragma("unroll") for (int d = 0; d < 8; ++d) {                       \
            int bw = __builtin_amdgcn_cvt_pk_bf8_f32(vv[d][0], vv[d][1], 0, false); \
            Bq[d]  = __builtin_amdgcn_cvt_pk_bf8_f32(vv[d][2], vv[d][3], bw, true); \
        }                                                                     \
    }                                                                         \
} while (0)

// xs = exp(emit), fp32 (memory-bound, full GPU).
__global__ __launch_bounds__(256) void crf_xs32_kernel(
    const float* __restrict__ emit, float* __restrict__ xs)
{
    const size_t i = (size_t)blockIdx.x * 256 + threadIdx.x;  // float4 index
    const float4 e = ((const float4*)emit)[i];
    float4 o;
    o.x = __builtin_amdgcn_exp2f(e.x * LOG2E);
    o.y = __builtin_amdgcn_exp2f(e.y * LOG2E);
    o.z = __builtin_amdgcn_exp2f(e.z * LOG2E);
    o.w = __builtin_amdgcn_exp2f(e.w * LOG2E);
    ((float4*)xs)[i] = o;
}

__global__ __launch_bounds__(64, 1) void crf_scan_mx_kernel(
    const float* __restrict__ emit,
    const float* __restrict__ xs,
    const float* __restrict__ Tm,
    float* __restrict__ scan_part)   // (256)
{
    const int gb = blockIdx.x;       // batch group 0..15
    const int l  = threadIdx.x;      // 0..63
    const int b  = l & 15;           // batch within group (MFMA m/n index)
    const int g  = l >> 4;           // 16-lane group (k-block index)
    const int bg = gb * 16 + b;
    const int lb = 32 * bg + g;      // per-lane float4 base index

    const f32x4* xsf = (const f32x4*)xs;
    const f32x4 zero4 = {0.f, 0.f, 0.f, 0.f};

    // ---- constant A (e4m3): Afr[jt] dword d byte c =
    // A[16jt+b][k~=32g+4d+c] = exp(T[16d+4g+c][16jt+b]) ----
    i32x8 Afr[8];
#pragma unroll
    for (int jt = 0; jt < 8; ++jt)
#pragma unroll
        for (int d = 0; d < 8; ++d) {
            const int col = 16 * jt + b;
            const int rb  = 16 * d + 4 * g;
            float a0 = __builtin_amdgcn_exp2f(Tm[(rb + 0) * 128 + col] * LOG2E);
            float a1 = __builtin_amdgcn_exp2f(Tm[(rb + 1) * 128 + col] * LOG2E);
            float a2 = __builtin_amdgcn_exp2f(Tm[(rb + 2) * 128 + col] * LOG2E);
            float a3 = __builtin_amdgcn_exp2f(Tm[(rb + 3) * 128 + col] * LOG2E);
            int w = __builtin_amdgcn_cvt_pk_fp8_f32(a0, a1, 0, false);
            Afr[jt][d] = __builtin_amdgcn_cvt_pk_fp8_f32(a2, a3, w, true);
        }

    // ---- t=0 init: V_0 = exp(emit[0]) -> bf8 Bq + initial scale ----
    i32x8 Bq;
    int ls2 = 0;
    int sclw;
    {
        float x0[8][4];
#pragma unroll
        for (int jt = 0; jt < 8; ++jt) {
            float4 e = ((const float4*)emit)[lb + 4 * jt];
            x0[jt][0] = __builtin_amdgcn_exp2f(e.x * LOG2E);
            x0[jt][1] = __builtin_amdgcn_exp2f(e.y * LOG2E);
            x0[jt][2] = __builtin_amdgcn_exp2f(e.z * LOG2E);
            x0[jt][3] = __builtin_amdgcn_exp2f(e.w * LOG2E);
        }
        float m8[8];
#pragma unroll
        for (int jt = 0; jt < 8; ++jt)
            m8[jt] = fmaxf(fmaxf(x0[jt][0], x0[jt][1]),
                           fmaxf(x0[jt][2], x0[jt][3]));
        float mx = fmaxf(fmaxf(fmaxf(m8[0], m8[1]), fmaxf(m8[2], m8[3])),
                         fmaxf(fmaxf(m8[4], m8[5]), fmaxf(m8[6], m8[7])));
        mx = fmaxf(mx, __shfl_xor(mx, 16));
        mx = fmaxf(mx, __shfl_xor(mx, 32));
        int Ee = (__float_as_int(mx) >> 23) & 0xFF;
        if (Ee < 16)  Ee = 16;
        if (Ee > 250) Ee = 250;
        ls2 += Ee - 125;
        sclw = (252 - Ee) * 0x01010101;
#pragma unroll
        for (int d = 0; d < 8; ++d) {
            int bw = __builtin_amdgcn_cvt_pk_bf8_f32(x0[d][0], x0[d][1], 0, false);
            Bq[d]  = __builtin_amdgcn_cvt_pk_bf8_f32(x0[d][2], x0[d][3], bw, true);
        }
    }

    // ---- prefetch t = 1..4 into 4 slots ----
    f32x4 xf[4][8];
#pragma unroll
    for (int k = 0; k < 4; ++k)
#pragma unroll
        for (int jt = 0; jt < 8; ++jt)
            xf[k][jt] = xsf[8192 * (1 + k) + lb + 4 * jt];

    float fin = 0.f;

    // ---- main loop: t = 1..508 (127 groups of 4) ----
#pragma unroll 1
    for (int grp = 0; grp < 127; ++grp) {
        const int t0 = 1 + 4 * grp;
        STEPX(0, t0 + 4, 1, 0);
        STEPX(1, t0 + 5, 1, 0);
        STEPX(2, t0 + 6, 1, 0);
        STEPX(3, t0 + 7, 1, 0);
    }
    // tail: t = 509, 510, 511
    STEPX(0, 0, 0, 0);
    STEPX(1, 0, 0, 0);
    STEPX(2, 0, 0, 1);

    // ---- finalize ----
    fin += __shfl_xor(fin, 16);
    fin += __shfl_xor(fin, 32);
    if (l < 16)
        scan_part[gb * 16 + l] = ((float)ls2 + __log2f(fin)) * LN2F;
}

// ---------------- bf16 fallback scan (R7 MODE-2 structure) ----------------
#define MFMAB(Aop, Bop, Cop) \
    __builtin_amdgcn_mfma_f32_16x16x32_bf16( \
        __builtin_bit_cast(bf16x8, Aop), __builtin_bit_cast(bf16x8, Bop), Cop, 0, 0, 0)

#define STEPB(SLOT, TPF, DOPF, RN, LAST) do {                                 \
    f32x4 ac[8];                                                              \
    _Pragma("unroll") for (int jt = 0; jt < 8; ++jt)                          \
        ac[jt] = MFMAB(Afr[0][jt], Bf[0], zero4);                             \
    _Pragma("unroll") for (int ch = 1; ch < 4; ++ch)                          \
        _Pragma("unroll") for (int jt = 0; jt < 8; ++jt)                      \
            ac[jt] = MFMAB(Afr[ch][jt], Bf[ch], ac[jt]);                      \
    float xv[8][4];                                                           \
    _Pragma("unroll") for (int jt = 0; jt < 8; ++jt) {                        \
        float4 xw = xbf[SLOT][jt];                                            \
        xv[jt][0] = __builtin_amdgcn_exp2f(xw.x * LOG2E);                     \
        xv[jt][1] = __builtin_amdgcn_exp2f(xw.y * LOG2E);                     \
        xv[jt][2] = __builtin_amdgcn_exp2f(xw.z * LOG2E);                     \
        xv[jt][3] = __builtin_amdgcn_exp2f(xw.w * LOG2E);                     \
    }                                                                         \
    if (DOPF) {                                                               \
        int tp = (TPF); if (tp > 511) tp = 511;                               \
        _Pragma("unroll") for (int jt = 0; jt < 8; ++jt)                      \
            xbf[SLOT][jt] = emf4[8192 * tp + lb + 4 * jt];                    \
    }                                                                         \
    float vv[8][4];                                                           \
    _Pragma("unroll") for (int jt = 0; jt < 8; ++jt)                          \
        _Pragma("unroll") for (int r = 0; r < 4; ++r)                         \
            vv[jt][r] = ac[jt][r] * xv[jt][r];                                \
    if (RN) {                                                                 \
        float mx = vv[0][0];                                                  \
        _Pragma("unroll") for (int jt = 0; jt < 8; ++jt)                      \
            _Pragma("unroll") for (int r = 0; r < 4; ++r)                     \
                mx = fmaxf(mx, vv[jt][r]);                                    \
        mx = fmaxf(mx, __shfl_xor(mx, 16));                                   \
        mx = fmaxf(mx, __shfl_xor(mx, 32));                                   \
        int Ee = (__float_as_int(mx) >> 23) & 0xFF;                           \
        if (Ee > 254) Ee = 254;                                               \
        ls2 += Ee - 127;                                                      \
        float scl = __int_as_float((254 - Ee) << 23);                         \
        _Pragma("unroll") for (int jt = 0; jt < 8; ++jt)                      \
            _Pragma("unroll") for (int r = 0; r < 4; ++r)                     \
                vv[jt][r] *= scl;                                             \
    }                                                                         \
    if (LAST) {                                                               \
        fin = 0.f;                                                            \
        _Pragma("unroll") for (int jt = 0; jt < 8; ++jt)                      \
            fin += (vv[jt][0] + vv[jt][1]) + (vv[jt][2] + vv[jt][3]);         \
    } else {                                                                  \
        _Pragma("unroll") for (int ch = 0; ch < 4; ++ch) {                    \
            Bf[ch][0] = packbf2(vv[2*ch][0],     vv[2*ch][1]);                \
            Bf[ch][1] = packbf2(vv[2*ch][2],     vv[2*ch][3]);                \
            Bf[ch][2] = packbf2(vv[2*ch + 1][0], vv[2*ch + 1][1]);            \
            Bf[ch][3] = packbf2(vv[2*ch + 1][2], vv[2*ch + 1][3]);            \
        }                                                                     \
    }                                                                         \
} while (0)

__global__ __launch_bounds__(64, 1) void crf_scan_bf16_kernel(
    const float* __restrict__ emit,
    const float* __restrict__ Tm,
    float* __restrict__ scan_part)   // (256)
{
    const int gb = blockIdx.x;
    const int l  = threadIdx.x;
    const int b  = l & 15;
    const int g  = l >> 4;
    const int bg = gb * 16 + b;
    const int lb = 32 * bg + g;

    const float4* emf4 = (const float4*)emit;
    const f32x4 zero4 = {0.f, 0.f, 0.f, 0.f};

    u32x4 Afr[4][8];
#pragma unroll
    for (int ch = 0; ch < 4; ++ch)
#pragma unroll
        for (int p = 0; p < 4; ++p) {
            const int e0 = 2 * p, e1 = 2 * p + 1;
            const int jp0 = 32 * ch + 16 * (e0 >> 2) + 4 * g + (e0 & 3);
            const int jp1 = 32 * ch + 16 * (e1 >> 2) + 4 * g + (e1 & 3);
#pragma unroll
            for (int jt = 0; jt < 8; ++jt) {
                float a0 = __builtin_amdgcn_exp2f(Tm[jp0 * 128 + 16 * jt + b] * LOG2E);
                float a1 = __builtin_amdgcn_exp2f(Tm[jp1 * 128 + 16 * jt + b] * LOG2E);
                Afr[ch][jt][p] = packbf2(a0, a1);
            }
        }

    u32x4 Bf[4];
    {
        float x0[8][4];
#pragma unroll
        for (int jt = 0; jt < 8; ++jt) {
            float4 e = emf4[lb + 4 * jt];
            x0[jt][0] = __builtin_amdgcn_exp2f(e.x * LOG2E);
            x0[jt][1] = __builtin_amdgcn_exp2f(e.y * LOG2E);
            x0[jt][2] = __builtin_amdgcn_exp2f(e.z * LOG2E);
            x0[jt][3] = __builtin_amdgcn_exp2f(e.w * LOG2E);
        }
#pragma unroll
        for (int ch = 0; ch < 4; ++ch) {
            Bf[ch][0] = packbf2(x0[2 * ch][0],     x0[2 * ch][1]);
            Bf[ch][1] = packbf2(x0[2 * ch][2],     x0[2 * ch][3]);
            Bf[ch][2] = packbf2(x0[2 * ch + 1][0], x0[2 * ch + 1][1]);
            Bf[ch][3] = packbf2(x0[2 * ch + 1][2], x0[2 * ch + 1][3]);
        }
    }

    float4 xbf[4][8];
#pragma unroll
    for (int k = 0; k < 4; ++k)
#pragma unroll
        for (int jt = 0; jt < 8; ++jt)
            xbf[k][jt] = emf4[8192 * (1 + k) + lb + 4 * jt];

    int ls2 = 0;
    float fin = 0.f;

#pragma unroll 1
    for (int grp = 0; grp < 63; ++grp) {
        const int t0 = 1 + 8 * grp;
        STEPB(0, t0 + 4,  1, 0, 0);
        STEPB(1, t0 + 5,  1, 0, 0);
        STEPB(2, t0 + 6,  1, 0, 0);
        STEPB(3, t0 + 7,  1, 0, 0);
        STEPB(0, t0 + 8,  1, 0, 0);
        STEPB(1, t0 + 9,  1, 0, 0);
        STEPB(2, t0 + 10, 1, 0, 0);
        STEPB(3, t0 + 11, 1, 1, 0);
    }
    STEPB(0, 509, 1, 0, 0);
    STEPB(1, 510, 1, 0, 0);
    STEPB(2, 511, 1, 0, 0);
    STEPB(3, 0,   0, 0, 0);
    STEPB(0, 0,   0, 0, 0);
    STEPB(1, 0,   0, 0, 0);
    STEPB(2, 0,   0, 0, 1);

    fin += __shfl_xor(fin, 16);
    fin += __shfl_xor(fin, 32);
    if (l < 16)
        scan_part[gb * 16 + l] = ((float)ls2 + __log2f(fin)) * LN2F;
}

__global__ __launch_bounds__(256) void crf_gold_kernel(
    const float* __restrict__ emit, const float* __restrict__ Tm,
    const int* __restrict__ labels, const int* __restrict__ startp,
    float* __restrict__ gold_part)   // (256)
{
    const int b = blockIdx.x, tid = threadIdx.x;
    __shared__ int lab[512];
    __shared__ float r[4];
    lab[tid]       = labels[b * 512 + tid];
    lab[tid + 256] = labels[b * 512 + tid + 256];
    __syncthreads();
    float s = 0.f;
    {
        int y0 = lab[tid];
        int p0 = (tid == 0) ? startp[0] : lab[tid - 1];
        s += emit[((size_t)tid * 256 + b) * 128 + y0] + Tm[p0 * 128 + y0];
        int t1 = tid + 256;
        int y1 = lab[t1];
        int p1 = lab[t1 - 1];
        s += emit[((size_t)t1 * 256 + b) * 128 + y1] + Tm[p1 * 128 + y1];
    }
#pragma unroll
    for (int off = 1; off < 64; off <<= 1) s += __shfl_xor(s, off);
    if ((tid & 63) == 0) r[tid >> 6] = s;
    __syncthreads();
    if (tid == 0) gold_part[b] = (r[0] + r[1]) + (r[2] + r[3]);
}

__global__ __launch_bounds__(256) void crf_final_kernel(
    const float* __restrict__ scan_part, const float* __restrict__ gold_part,
    float* __restrict__ out)
{
    const int tid = threadIdx.x;
    __shared__ float r[4];
    float v = scan_part[tid] - gold_part[tid];
#pragma unroll
    for (int off = 1; off < 64; off <<= 1) v += __shfl_xor(v, off);
    if ((tid & 63) == 0) r[tid >> 6] = v;
    __syncthreads();
    if (tid == 0) out[0] = (r[0] + r[1]) + (r[2] + r[3]);
}

extern "C" void kernel_launch(void* const* d_in, const int* in_sizes, int n_in,
                              void* d_out, int out_size, void* d_ws, size_t ws_size,
                              hipStream_t stream) {
    const float* emit   = (const float*)d_in[0];
    const float* Tm     = (const float*)d_in[1];
    const int*   labels = (const int*)d_in[2];
    const int*   startp = (const int*)d_in[3];

    const size_t xs32_bytes = (size_t)512 * 256 * 128 * 4;   // 67,108,864

    if (ws_size >= xs32_bytes + 2048) {
        float* xs        = (float*)d_ws;
        float* scan_part = (float*)((char*)d_ws + xs32_bytes);
        float* gold_part = scan_part + 256;
        crf_xs32_kernel<<<16384, 256, 0, stream>>>(emit, xs);
        crf_scan_mx_kernel<<<16, 64, 0, stream>>>(emit, xs, Tm, scan_part);
        crf_gold_kernel<<<256, 256, 0, stream>>>(emit, Tm, labels, startp, gold_part);
        crf_final_kernel<<<1, 256, 0, stream>>>(scan_part, gold_part, (float*)d_out);
    } else {
        float* scan_part = (float*)d_ws;
        float* gold_part = scan_part + 256;
        crf_scan_bf16_kernel<<<16, 64, 0, stream>>>(emit, Tm, scan_part);
        crf_gold_kernel<<<256, 256, 0, stream>>>(emit, Tm, labels, startp, gold_part);
        crf_final_kernel<<<1, 256, 0, stream>>>(scan_part, gold_part, (float*)d_out);
    }
}

// Round 9
// 208.248 us; speedup vs baseline: 1.9353x; 1.0865x over previous
//
#include <hip/hip_runtime.h>

// CRF loss, S=512, B=256, L=128; out = sum_b log_z_b - gold.
//
// R9 fast scan: per step 8x mfma_scale_f32_16x16x128_f8f6f4 (K=128 each) +
// NO max-reduce: per-step power-of-2 scale estimated from ONE element.
//   - ac_j = sum_i w_i E_ij varies across j by <= maxE/minE ~ 2.3 (E in
//     [0.66,1.52]) => e(max ac) <= e(ac[any j]) + 1.2 bits.
//   - x rows prenormalized by crf_xsn_kernel: xh = x*2^-X, max in [1,2),
//     X[b][t] int32 => e(max vv) ~ e(ac00) within ~2.5 bits.
//   => scale byte = 250 - exponent_field(shfl(ac00, b)), margin 4 bits.
//   Range: s*ymax in [2^-5.3, 2^-1.8]; y_next <= 2^6.8 << bf8 max 2^15.8;
//   flush floor 2^-16 => >= 2^8.8 relative range kept. ls2 bookkeeping:
//   L += X_t (slot-prefetched) + (127 - byte) integer adds.
//
// Layouts (R5-R8 verified): B byte e=4d+c of dword d holds k~=32g+4d+c;
// D tile d reg r (j=16d+4g+r) stores at byte 4d+r; A[j][k~] =
// exp(T[pi^-1(k~)][j]), pi^-1(32g'+4d+c)=16d+4g'+c. A e4m3 (cbsz=0),
// W e5m2 (blgp=1), per-column scale uniform across the 4 g-lanes (shfl).
//
// Fallbacks: [ws >= xh+X+2048: fast] [ws >= xs+2048: R8 exact-max kernel,
// proven] [else: bf16 in-register scan].

#define LOG2E 1.4426950408889634f
#define LN2F  0.6931471805599453f

typedef float        f32x4  __attribute__((ext_vector_type(4)));
typedef int          i32x8  __attribute__((ext_vector_type(8)));
typedef unsigned int u32x4  __attribute__((ext_vector_type(4)));
typedef short        bf16x8 __attribute__((ext_vector_type(8)));
typedef __bf16       bf16x2 __attribute__((ext_vector_type(2)));

__device__ __forceinline__ unsigned packbf2(float lo, float hi) {
    bf16x2 p = { (__bf16)lo, (__bf16)hi };   // RNE -> v_cvt_pk_bf16_f32
    return __builtin_bit_cast(unsigned, p);
}

// ================= xs prenormalize kernel =================
// Row (t,b) of 128: xh = exp(emit)*2^-X with row max in [1,2); X[b][t] int.
// Block = 256 thr = 16 rows x 16 threads; thread handles 8 floats.
__global__ __launch_bounds__(256) void crf_xsn_kernel(
    const float* __restrict__ emit, float* __restrict__ xh,
    int* __restrict__ X)
{
    const int tid = threadIdx.x;
    const int r   = blockIdx.x * 16 + (tid >> 4);   // row index = t*256 + b
    const int s   = tid & 15;
    const float4* src = (const float4*)emit + (size_t)r * 32 + s * 2;
    float4 e0 = src[0], e1 = src[1];
    float x0 = __builtin_amdgcn_exp2f(e0.x * LOG2E);
    float x1 = __builtin_amdgcn_exp2f(e0.y * LOG2E);
    float x2 = __builtin_amdgcn_exp2f(e0.z * LOG2E);
    float x3 = __builtin_amdgcn_exp2f(e0.w * LOG2E);
    float x4 = __builtin_amdgcn_exp2f(e1.x * LOG2E);
    float x5 = __builtin_amdgcn_exp2f(e1.y * LOG2E);
    float x6 = __builtin_amdgcn_exp2f(e1.z * LOG2E);
    float x7 = __builtin_amdgcn_exp2f(e1.w * LOG2E);
    float m = fmaxf(fmaxf(fmaxf(x0, x1), fmaxf(x2, x3)),
                    fmaxf(fmaxf(x4, x5), fmaxf(x6, x7)));
#pragma unroll
    for (int off = 1; off < 16; off <<= 1)
        m = fmaxf(m, __shfl_xor(m, off));
    const int eb = (__float_as_int(m) >> 23) & 0xFF;
    const float scl = __int_as_float((254 - eb) << 23);   // 2^(127-eb)
    float4 o0, o1;
    o0.x = x0 * scl; o0.y = x1 * scl; o0.z = x2 * scl; o0.w = x3 * scl;
    o1.x = x4 * scl; o1.y = x5 * scl; o1.z = x6 * scl; o1.w = x7 * scl;
    float4* dst = (float4*)xh + (size_t)r * 32 + s * 2;
    dst[0] = o0; dst[1] = o1;
    if (s == 0) X[(r & 255) * 512 + (r >> 8)] = eb - 127;  // X[b][t]
}

// ================= R9 fast scan =================
// Kernel scope: Afr, Bq, sclw, zero4, xf, Xs, xhf, Xi, lb, b, L, fin.
#define STEPF(SLOT, TPF, DOPF, LAST) do {                                     \
    f32x4 ac[8];                                                              \
    _Pragma("unroll") for (int jt = 0; jt < 8; ++jt)                          \
        ac[jt] = __builtin_amdgcn_mfma_scale_f32_16x16x128_f8f6f4(            \
            Afr[jt], Bq, zero4, 0, 1, 0, 0x7F7F7F7F, 0, sclw);                \
    {   /* next-step scale from one element (spread <= 2.3 proof) */          \
        float a00 = __shfl(ac[0][0], b);                                      \
        int ea = (__float_as_int(a00) >> 23) & 0xFF;                          \
        int sb = 250 - ea;                                                    \
        sb = sb < 1 ? 1 : (sb > 254 ? 254 : sb);                              \
        L += Xs[SLOT];                                                        \
        if (!(LAST)) { L += 127 - sb; sclw = sb * 0x01010101; }               \
    }                                                                         \
    f32x4 vv[8];                                                              \
    _Pragma("unroll") for (int jt = 0; jt < 8; ++jt)                          \
        vv[jt] = ac[jt] * xf[SLOT][jt];                                       \
    if (DOPF) {                                                               \
        int tp = (TPF); if (tp > 511) tp = 511;                               \
        _Pragma("unroll") for (int jt = 0; jt < 8; ++jt)                      \
            xf[SLOT][jt] = xhf[8192 * tp + lb + 4 * jt];                      \
        Xs[SLOT] = Xi[tp];                                                    \
    }                                                                         \
    if (LAST) {                                                               \
        fin = 0.f;                                                            \
        _Pragma("unroll") for (int jt = 0; jt < 8; ++jt)                      \
            fin += (vv[jt][0] + vv[jt][1]) + (vv[jt][2] + vv[jt][3]);         \
    } else {                                                                  \
        _Pragma("unroll") for (int d = 0; d < 8; ++d) {                       \
            int bw = __builtin_amdgcn_cvt_pk_bf8_f32(vv[d][0], vv[d][1], 0, false); \
            Bq[d]  = __builtin_amdgcn_cvt_pk_bf8_f32(vv[d][2], vv[d][3], bw, true); \
        }                                                                     \
    }                                                                         \
} while (0)

__global__ __launch_bounds__(64, 1) void crf_scan_fast_kernel(
    const float* __restrict__ xh,
    const int*   __restrict__ X,
    const float* __restrict__ Tm,
    float* __restrict__ scan_part)   // (256)
{
    const int gb = blockIdx.x;       // batch group 0..15
    const int l  = threadIdx.x;      // 0..63
    const int b  = l & 15;           // batch within group (MFMA m/n index)
    const int g  = l >> 4;           // 16-lane group (k-block index)
    const int bg = gb * 16 + b;
    const int lb = 32 * bg + g;      // per-lane float4 base index

    const f32x4* xhf = (const f32x4*)xh;
    const int*   Xi  = X + bg * 512;
    const f32x4 zero4 = {0.f, 0.f, 0.f, 0.f};

    // ---- constant A (e4m3): Afr[jt] dword d byte c =
    // A[16jt+b][k~=32g+4d+c] = exp(T[16d+4g+c][16jt+b]) ----
    i32x8 Afr[8];
#pragma unroll
    for (int jt = 0; jt < 8; ++jt)
#pragma unroll
        for (int d = 0; d < 8; ++d) {
            const int col = 16 * jt + b;
            const int rb  = 16 * d + 4 * g;
            float a0 = __builtin_amdgcn_exp2f(Tm[(rb + 0) * 128 + col] * LOG2E);
            float a1 = __builtin_amdgcn_exp2f(Tm[(rb + 1) * 128 + col] * LOG2E);
            float a2 = __builtin_amdgcn_exp2f(Tm[(rb + 2) * 128 + col] * LOG2E);
            float a3 = __builtin_amdgcn_exp2f(Tm[(rb + 3) * 128 + col] * LOG2E);
            int w = __builtin_amdgcn_cvt_pk_fp8_f32(a0, a1, 0, false);
            Afr[jt][d] = __builtin_amdgcn_cvt_pk_fp8_f32(a2, a3, w, true);
        }

    // ---- t=0 init: y0 = cvt_bf8(xh[0]); L = X0 + 4; scale = 2^-4 ----
    i32x8 Bq;
    int L;
    int sclw = 123 * 0x01010101;
    {
        f32x4 x0[8];
#pragma unroll
        for (int jt = 0; jt < 8; ++jt) x0[jt] = xhf[lb + 4 * jt];
#pragma unroll
        for (int d = 0; d < 8; ++d) {
            int bw = __builtin_amdgcn_cvt_pk_bf8_f32(x0[d][0], x0[d][1], 0, false);
            Bq[d]  = __builtin_amdgcn_cvt_pk_bf8_f32(x0[d][2], x0[d][3], bw, true);
        }
        L = Xi[0] + 4;
    }

    // ---- prefetch t = 1..4 into 4 slots ----
    f32x4 xf[4][8];
    int   Xs[4];
#pragma unroll
    for (int k = 0; k < 4; ++k) {
#pragma unroll
        for (int jt = 0; jt < 8; ++jt)
            xf[k][jt] = xhf[8192 * (1 + k) + lb + 4 * jt];
        Xs[k] = Xi[1 + k];
    }

    float fin = 0.f;

    // ---- main loop: t = 1..508 (127 groups of 4) ----
#pragma unroll 1
    for (int grp = 0; grp < 127; ++grp) {
        const int t0 = 1 + 4 * grp;
        STEPF(0, t0 + 4, 1, 0);
        STEPF(1, t0 + 5, 1, 0);
        STEPF(2, t0 + 6, 1, 0);
        STEPF(3, t0 + 7, 1, 0);
    }
    // tail: t = 509, 510, 511 (slots 0,1,2)
    STEPF(0, 0, 0, 0);
    STEPF(1, 0, 0, 0);
    STEPF(2, 0, 0, 1);

    // ---- finalize: combine 4 g-lanes; log_z = (L + log2(sum)) * ln2 ----
    fin += __shfl_xor(fin, 16);
    fin += __shfl_xor(fin, 32);
    if (l < 16)
        scan_part[gb * 16 + l] = ((float)L + __log2f(fin)) * LN2F;
}

// ================= R8 exact-max scan (proven; middle fallback) ============
#define STEPM(SLOT, TPF, DOPF, LAST) do {                                     \
    f32x4 ac[8];                                                              \
    _Pragma("unroll") for (int jt = 0; jt < 8; ++jt)                          \
        ac[jt] = __builtin_amdgcn_mfma_scale_f32_16x16x128_f8f6f4(            \
            Afr[jt], Bq, zero4, 0, 1, 0, 0x7F7F7F7F, 0, sclw);                \
    float vv[8][4];                                                           \
    _Pragma("unroll") for (int jt = 0; jt < 8; ++jt) {                        \
        f32x4 xw = xf[SLOT][jt];                                              \
        vv[jt][0] = ac[jt][0] * xw[0];                                        \
        vv[jt][1] = ac[jt][1] * xw[1];                                        \
        vv[jt][2] = ac[jt][2] * xw[2];                                        \
        vv[jt][3] = ac[jt][3] * xw[3];                                        \
    }                                                                         \
    if (DOPF) {                                                               \
        int tp = (TPF); if (tp > 511) tp = 511;                               \
        _Pragma("unroll") for (int jt = 0; jt < 8; ++jt)                      \
            xf[SLOT][jt] = xsf[8192 * tp + lb + 4 * jt];                      \
    }                                                                         \
    if (LAST) {                                                               \
        fin = 0.f;                                                            \
        _Pragma("unroll") for (int jt = 0; jt < 8; ++jt)                      \
            fin += (vv[jt][0] + vv[jt][1]) + (vv[jt][2] + vv[jt][3]);         \
    } else {                                                                  \
        float m8[8];                                                          \
        _Pragma("unroll") for (int jt = 0; jt < 8; ++jt)                      \
            m8[jt] = fmaxf(fmaxf(vv[jt][0], vv[jt][1]),                       \
                           fmaxf(vv[jt][2], vv[jt][3]));                      \
        float mx = fmaxf(fmaxf(fmaxf(m8[0], m8[1]), fmaxf(m8[2], m8[3])),     \
                         fmaxf(fmaxf(m8[4], m8[5]), fmaxf(m8[6], m8[7])));    \
        mx = fmaxf(mx, __shfl_xor(mx, 16));                                   \
        mx = fmaxf(mx, __shfl_xor(mx, 32));                                   \
        int Ee = (__float_as_int(mx) >> 23) & 0xFF;                           \
        if (Ee < 16)  Ee = 16;                                                \
        if (Ee > 250) Ee = 250;                                               \
        ls2 += Ee - 125;                                                      \
        sclw = (252 - Ee) * 0x01010101;                                       \
        _Pragma("unroll") for (int d = 0; d < 8; ++d) {                       \
            int bw = __builtin_amdgcn_cvt_pk_bf8_f32(vv[d][0], vv[d][1], 0, false); \
            Bq[d]  = __builtin_amdgcn_cvt_pk_bf8_f32(vv[d][2], vv[d][3], bw, true); \
        }                                                                     \
    }                                                                         \
} while (0)

__global__ __launch_bounds__(256) void crf_xs32_kernel(
    const float* __restrict__ emit, float* __restrict__ xs)
{
    const size_t i = (size_t)blockIdx.x * 256 + threadIdx.x;
    const float4 e = ((const float4*)emit)[i];
    float4 o;
    o.x = __builtin_amdgcn_exp2f(e.x * LOG2E);
    o.y = __builtin_amdgcn_exp2f(e.y * LOG2E);
    o.z = __builtin_amdgcn_exp2f(e.z * LOG2E);
    o.w = __builtin_amdgcn_exp2f(e.w * LOG2E);
    ((float4*)xs)[i] = o;
}

__global__ __launch_bounds__(64, 1) void crf_scan_mx_kernel(
    const float* __restrict__ emit,
    const float* __restrict__ xs,
    const float* __restrict__ Tm,
    float* __restrict__ scan_part)
{
    const int gb = blockIdx.x;
    const int l  = threadIdx.x;
    const int b  = l & 15;
    const int g  = l >> 4;
    const int bg = gb * 16 + b;
    const int lb = 32 * bg + g;

    const f32x4* xsf = (const f32x4*)xs;
    const f32x4 zero4 = {0.f, 0.f, 0.f, 0.f};

    i32x8 Afr[8];
#pragma unroll
    for (int jt = 0; jt < 8; ++jt)
#pragma unroll
        for (int d = 0; d < 8; ++d) {
            const int col = 16 * jt + b;
            const int rb  = 16 * d + 4 * g;
            float a0 = __builtin_amdgcn_exp2f(Tm[(rb + 0) * 128 + col] * LOG2E);
            float a1 = __builtin_amdgcn_exp2f(Tm[(rb + 1) * 128 + col] * LOG2E);
            float a2 = __builtin_amdgcn_exp2f(Tm[(rb + 2) * 128 + col] * LOG2E);
            float a3 = __builtin_amdgcn_exp2f(Tm[(rb + 3) * 128 + col] * LOG2E);
            int w = __builtin_amdgcn_cvt_pk_fp8_f32(a0, a1, 0, false);
            Afr[jt][d] = __builtin_amdgcn_cvt_pk_fp8_f32(a2, a3, w, true);
        }

    i32x8 Bq;
    int ls2 = 0;
    int sclw;
    {
        float x0[8][4];
#pragma unroll
        for (int jt = 0; jt < 8; ++jt) {
            float4 e = ((const float4*)emit)[lb + 4 * jt];
            x0[jt][0] = __builtin_amdgcn_exp2f(e.x * LOG2E);
            x0[jt][1] = __builtin_amdgcn_exp2f(e.y * LOG2E);
            x0[jt][2] = __builtin_amdgcn_exp2f(e.z * LOG2E);
            x0[jt][3] = __builtin_amdgcn_exp2f(e.w * LOG2E);
        }
        float m8[8];
#pragma unroll
        for (int jt = 0; jt < 8; ++jt)
            m8[jt] = fmaxf(fmaxf(x0[jt][0], x0[jt][1]),
                           fmaxf(x0[jt][2], x0[jt][3]));
        float mx = fmaxf(fmaxf(fmaxf(m8[0], m8[1]), fmaxf(m8[2], m8[3])),
                         fmaxf(fmaxf(m8[4], m8[5]), fmaxf(m8[6], m8[7])));
        mx = fmaxf(mx, __shfl_xor(mx, 16));
        mx = fmaxf(mx, __shfl_xor(mx, 32));
        int Ee = (__float_as_int(mx) >> 23) & 0xFF;
        if (Ee < 16)  Ee = 16;
        if (Ee > 250) Ee = 250;
        ls2 += Ee - 125;
        sclw = (252 - Ee) * 0x01010101;
#pragma unroll
        for (int d = 0; d < 8; ++d) {
            int bw = __builtin_amdgcn_cvt_pk_bf8_f32(x0[d][0], x0[d][1], 0, false);
            Bq[d]  = __builtin_amdgcn_cvt_pk_bf8_f32(x0[d][2], x0[d][3], bw, true);
        }
    }

    f32x4 xf[4][8];
#pragma unroll
    for (int k = 0; k < 4; ++k)
#pragma unroll
        for (int jt = 0; jt < 8; ++jt)
            xf[k][jt] = xsf[8192 * (1 + k) + lb + 4 * jt];

    float fin = 0.f;

#pragma unroll 1
    for (int grp = 0; grp < 127; ++grp) {
        const int t0 = 1 + 4 * grp;
        STEPM(0, t0 + 4, 1, 0);
        STEPM(1, t0 + 5, 1, 0);
        STEPM(2, t0 + 6, 1, 0);
        STEPM(3, t0 + 7, 1, 0);
    }
    STEPM(0, 0, 0, 0);
    STEPM(1, 0, 0, 0);
    STEPM(2, 0, 0, 1);

    fin += __shfl_xor(fin, 16);
    fin += __shfl_xor(fin, 32);
    if (l < 16)
        scan_part[gb * 16 + l] = ((float)ls2 + __log2f(fin)) * LN2F;
}

// ================= bf16 fallback scan (R7 structure) =================
#define MFMAB(Aop, Bop, Cop) \
    __builtin_amdgcn_mfma_f32_16x16x32_bf16( \
        __builtin_bit_cast(bf16x8, Aop), __builtin_bit_cast(bf16x8, Bop), Cop, 0, 0, 0)

#define STEPB(SLOT, TPF, DOPF, RN, LAST) do {                                 \
    f32x4 ac[8];                                                              \
    _Pragma("unroll") for (int jt = 0; jt < 8; ++jt)                          \
        ac[jt] = MFMAB(Afr[0][jt], Bf[0], zero4);                             \
    _Pragma("unroll") for (int ch = 1; ch < 4; ++ch)                          \
        _Pragma("unroll") for (int jt = 0; jt < 8; ++jt)                      \
            ac[jt] = MFMAB(Afr[ch][jt], Bf[ch], ac[jt]);                      \
    float xv[8][4];                                                           \
    _Pragma("unroll") for (int jt = 0; jt < 8; ++jt) {                        \
        float4 xw = xbf[SLOT][jt];                                            \
        xv[jt][0] = __builtin_amdgcn_exp2f(xw.x * LOG2E);                     \
        xv[jt][1] = __builtin_amdgcn_exp2f(xw.y * LOG2E);                     \
        xv[jt][2] = __builtin_amdgcn_exp2f(xw.z * LOG2E);                     \
        xv[jt][3] = __builtin_amdgcn_exp2f(xw.w * LOG2E);                     \
    }                                                                         \
    if (DOPF) {                                                               \
        int tp = (TPF); if (tp > 511) tp = 511;                               \
        _Pragma("unroll") for (int jt = 0; jt < 8; ++jt)                      \
            xbf[SLOT][jt] = emf4[8192 * tp + lb + 4 * jt];                    \
    }                                                                         \
    float vv[8][4];                                                           \
    _Pragma("unroll") for (int jt = 0; jt < 8; ++jt)                          \
        _Pragma("unroll") for (int r = 0; r < 4; ++r)                         \
            vv[jt][r] = ac[jt][r] * xv[jt][r];                                \
    if (RN) {                                                                 \
        float mx = vv[0][0];                                                  \
        _Pragma("unroll") for (int jt = 0; jt < 8; ++jt)                      \
            _Pragma("unroll") for (int r = 0; r < 4; ++r)                     \
                mx = fmaxf(mx, vv[jt][r]);                                    \
        mx = fmaxf(mx, __shfl_xor(mx, 16));                                   \
        mx = fmaxf(mx, __shfl_xor(mx, 32));                                   \
        int Ee = (__float_as_int(mx) >> 23) & 0xFF;                           \
        if (Ee > 254) Ee = 254;                                               \
        ls2 += Ee - 127;                                                      \
        float scl = __int_as_float((254 - Ee) << 23);                         \
        _Pragma("unroll") for (int jt = 0; jt < 8; ++jt)                      \
            _Pragma("unroll") for (int r = 0; r < 4; ++r)                     \
                vv[jt][r] *= scl;                                             \
    }                                                                         \
    if (LAST) {                                                               \
        fin = 0.f;                                                            \
        _Pragma("unroll") for (int jt = 0; jt < 8; ++jt)                      \
            fin += (vv[jt][0] + vv[jt][1]) + (vv[jt][2] + vv[jt][3]);         \
    } else {                                                                  \
        _Pragma("unroll") for (int ch = 0; ch < 4; ++ch) {                    \
            Bf[ch][0] = packbf2(vv[2*ch][0],     vv[2*ch][1]);                \
            Bf[ch][1] = packbf2(vv[2*ch][2],     vv[2*ch][3]);                \
            Bf[ch][2] = packbf2(vv[2*ch + 1][0], vv[2*ch + 1][1]);            \
            Bf[ch][3] = packbf2(vv[2*ch + 1][2], vv[2*ch + 1][3]);            \
        }                                                                     \
    }                                                                         \
} while (0)

__global__ __launch_bounds__(64, 1) void crf_scan_bf16_kernel(
    const float* __restrict__ emit,
    const float* __restrict__ Tm,
    float* __restrict__ scan_part)
{
    const int gb = blockIdx.x;
    const int l  = threadIdx.x;
    const int b  = l & 15;
    const int g  = l >> 4;
    const int bg = gb * 16 + b;
    const int lb = 32 * bg + g;

    const float4* emf4 = (const float4*)emit;
    const f32x4 zero4 = {0.f, 0.f, 0.f, 0.f};

    u32x4 Afr[4][8];
#pragma unroll
    for (int ch = 0; ch < 4; ++ch)
#pragma unroll
        for (int p = 0; p < 4; ++p) {
            const int e0 = 2 * p, e1 = 2 * p + 1;
            const int jp0 = 32 * ch + 16 * (e0 >> 2) + 4 * g + (e0 & 3);
            const int jp1 = 32 * ch + 16 * (e1 >> 2) + 4 * g + (e1 & 3);
#pragma unroll
            for (int jt = 0; jt < 8; ++jt) {
                float a0 = __builtin_amdgcn_exp2f(Tm[jp0 * 128 + 16 * jt + b] * LOG2E);
                float a1 = __builtin_amdgcn_exp2f(Tm[jp1 * 128 + 16 * jt + b] * LOG2E);
                Afr[ch][jt][p] = packbf2(a0, a1);
            }
        }

    u32x4 Bf[4];
    {
        float x0[8][4];
#pragma unroll
        for (int jt = 0; jt < 8; ++jt) {
            float4 e = emf4[lb + 4 * jt];
            x0[jt][0] = __builtin_amdgcn_exp2f(e.x * LOG2E);
            x0[jt][1] = __builtin_amdgcn_exp2f(e.y * LOG2E);
            x0[jt][2] = __builtin_amdgcn_exp2f(e.z * LOG2E);
            x0[jt][3] = __builtin_amdgcn_exp2f(e.w * LOG2E);
        }
#pragma unroll
        for (int ch = 0; ch < 4; ++ch) {
            Bf[ch][0] = packbf2(x0[2 * ch][0],     x0[2 * ch][1]);
            Bf[ch][1] = packbf2(x0[2 * ch][2],     x0[2 * ch][3]);
            Bf[ch][2] = packbf2(x0[2 * ch + 1][0], x0[2 * ch + 1][1]);
            Bf[ch][3] = packbf2(x0[2 * ch + 1][2], x0[2 * ch + 1][3]);
        }
    }

    float4 xbf[4][8];
#pragma unroll
    for (int k = 0; k < 4; ++k)
#pragma unroll
        for (int jt = 0; jt < 8; ++jt)
            xbf[k][jt] = emf4[8192 * (1 + k) + lb + 4 * jt];

    int ls2 = 0;
    float fin = 0.f;

#pragma unroll 1
    for (int grp = 0; grp < 63; ++grp) {
        const int t0 = 1 + 8 * grp;
        STEPB(0, t0 + 4,  1, 0, 0);
        STEPB(1, t0 + 5,  1, 0, 0);
        STEPB(2, t0 + 6,  1, 0, 0);
        STEPB(3, t0 + 7,  1, 0, 0);
        STEPB(0, t0 + 8,  1, 0, 0);
        STEPB(1, t0 + 9,  1, 0, 0);
        STEPB(2, t0 + 10, 1, 0, 0);
        STEPB(3, t0 + 11, 1, 1, 0);
    }
    STEPB(0, 509, 1, 0, 0);
    STEPB(1, 510, 1, 0, 0);
    STEPB(2, 511, 1, 0, 0);
    STEPB(3, 0,   0, 0, 0);
    STEPB(0, 0,   0, 0, 0);
    STEPB(1, 0,   0, 0, 0);
    STEPB(2, 0,   0, 0, 1);

    fin += __shfl_xor(fin, 16);
    fin += __shfl_xor(fin, 32);
    if (l < 16)
        scan_part[gb * 16 + l] = ((float)ls2 + __log2f(fin)) * LN2F;
}

// ================= gold + final =================
__global__ __launch_bounds__(256) void crf_gold_kernel(
    const float* __restrict__ emit, const float* __restrict__ Tm,
    const int* __restrict__ labels, const int* __restrict__ startp,
    float* __restrict__ gold_part)
{
    const int b = blockIdx.x, tid = threadIdx.x;
    __shared__ int lab[512];
    __shared__ float r[4];
    lab[tid]       = labels[b * 512 + tid];
    lab[tid + 256] = labels[b * 512 + tid + 256];
    __syncthreads();
    float s = 0.f;
    {
        int y0 = lab[tid];
        int p0 = (tid == 0) ? startp[0] : lab[tid - 1];
        s += emit[((size_t)tid * 256 + b) * 128 + y0] + Tm[p0 * 128 + y0];
        int t1 = tid + 256;
        int y1 = lab[t1];
        int p1 = lab[t1 - 1];
        s += emit[((size_t)t1 * 256 + b) * 128 + y1] + Tm[p1 * 128 + y1];
    }
#pragma unroll
    for (int off = 1; off < 64; off <<= 1) s += __shfl_xor(s, off);
    if ((tid & 63) == 0) r[tid >> 6] = s;
    __syncthreads();
    if (tid == 0) gold_part[b] = (r[0] + r[1]) + (r[2] + r[3]);
}

__global__ __launch_bounds__(256) void crf_final_kernel(
    const float* __restrict__ scan_part, const float* __restrict__ gold_part,
    float* __restrict__ out)
{
    const int tid = threadIdx.x;
    __shared__ float r[4];
    float v = scan_part[tid] - gold_part[tid];
#pragma unroll
    for (int off = 1; off < 64; off <<= 1) v += __shfl_xor(v, off);
    if ((tid & 63) == 0) r[tid >> 6] = v;
    __syncthreads();
    if (tid == 0) out[0] = (r[0] + r[1]) + (r[2] + r[3]);
}

extern "C" void kernel_launch(void* const* d_in, const int* in_sizes, int n_in,
                              void* d_out, int out_size, void* d_ws, size_t ws_size,
                              hipStream_t stream) {
    const float* emit   = (const float*)d_in[0];
    const float* Tm     = (const float*)d_in[1];
    const int*   labels = (const int*)d_in[2];
    const int*   startp = (const int*)d_in[3];

    const size_t xh_bytes = (size_t)512 * 256 * 128 * 4;   // 67,108,864
    const size_t X_bytes  = (size_t)256 * 512 * 4;         // 524,288

    if (ws_size >= xh_bytes + X_bytes + 2048) {
        float* xh        = (float*)d_ws;
        int*   X         = (int*)((char*)d_ws + xh_bytes);
        float* scan_part = (float*)((char*)d_ws + xh_bytes + X_bytes);
        float* gold_part = scan_part + 256;
        crf_xsn_kernel<<<8192, 256, 0, stream>>>(emit, xh, X);
        crf_scan_fast_kernel<<<16, 64, 0, stream>>>(xh, X, Tm, scan_part);
        crf_gold_kernel<<<256, 256, 0, stream>>>(emit, Tm, labels, startp, gold_part);
        crf_final_kernel<<<1, 256, 0, stream>>>(scan_part, gold_part, (float*)d_out);
    } else if (ws_size >= xh_bytes + 2048) {
        float* xs        = (float*)d_ws;
        float* scan_part = (float*)((char*)d_ws + xh_bytes);
        float* gold_part = scan_part + 256;
        crf_xs32_kernel<<<16384, 256, 0, stream>>>(emit, xs);
        crf_scan_mx_kernel<<<16, 64, 0, stream>>>(emit, xs, Tm, scan_part);
        crf_gold_kernel<<<256, 256, 0, stream>>>(emit, Tm, labels, startp, gold_part);
        crf_final_kernel<<<1, 256, 0, stream>>>(scan_part, gold_part, (float*)d_out);
    } else {
        float* scan_part = (float*)d_ws;
        float* gold_part = scan_part + 256;
        crf_scan_bf16_kernel<<<16, 64, 0, stream>>>(emit, Tm, scan_part);
        crf_gold_kernel<<<256, 256, 0, stream>>>(emit, Tm, labels, startp, gold_part);
        crf_final_kernel<<<1, 256, 0, stream>>>(scan_part, gold_part, (float*)d_out);
    }
}